// Round 7
// baseline (244.194 us; speedup 1.0000x reference)
//
#include <hip/hip_runtime.h>

#define N_NODES 50000
#define N_EDGES 800000
#define NBUCK   392           // buckets of 128 nodes (dst >> 7)
#define EPB     2048          // edges per scatter block
#define NSB     391           // scatter blocks = ceil(800000/2048)
#define CAPB    2560          // per-bucket capacity (mean ~2041, +11 sigma)

typedef __attribute__((ext_vector_type(8))) short short8;
typedef __attribute__((ext_vector_type(4))) float floatx4;

__device__ __forceinline__ float ubits(unsigned int b) {
    union { unsigned int i; float f; } v;
    v.i = b;
    return v.f;
}
__device__ __forceinline__ unsigned short f2b(float f) {  // round-nearest-even
    union { float f; unsigned int i; } v;
    v.f = f;
    unsigned int r = v.i + 0x7FFFu + ((v.i >> 16) & 1u);
    return (unsigned short)(r >> 16);
}

// ---------------------------------------------------------------------------
// K1a: per-(block,bucket) histogram (LDS, no global atomics) + all conversions.
// [0,391): hist block k -> cnt[b*391+k].  [391,903): weights.  [903,927): Wfct.
// [927,4052): x -> bf16.
// ---------------------------------------------------------------------------
__global__ __launch_bounds__(256) void hist_conv(
    const int* __restrict__ dstv, const float* __restrict__ x,
    const float* __restrict__ W11, const float* __restrict__ W12,
    const float* __restrict__ W21, const float* __restrict__ W22,
    const float* __restrict__ Wfc,
    int* __restrict__ cnt, unsigned short* __restrict__ xb,
    unsigned short* __restrict__ Wt11, unsigned short* __restrict__ Wt12,
    unsigned short* __restrict__ Wt21, unsigned short* __restrict__ Wt22,
    unsigned short* __restrict__ Wfct) {
    const int bid = blockIdx.x;
    const int tid = threadIdx.x;
    if (bid < NSB) {
        __shared__ int hist[NBUCK];
        const int k = bid;
        const int e0 = k * EPB;
        for (int i = tid; i < NBUCK; i += 256) hist[i] = 0;
        __syncthreads();
#pragma unroll
        for (int j = 0; j < EPB / 256; ++j) {
            int e = e0 + j * 256 + tid;
            if (e < N_EDGES) atomicAdd(&hist[dstv[e] >> 7], 1);
        }
        __syncthreads();
        for (int i = tid; i < NBUCK; i += 256) cnt[i * NSB + k] = hist[i];
    } else if (bid < NSB + 512) {
        int wb = bid - NSB;
        int which = wb >> 7;
        int idx = (wb & 127) * 256 + tid;
        const float* W = (which == 0) ? W11 : (which == 1) ? W12 : (which == 2) ? W21 : W22;
        unsigned short* Wt = (which == 0) ? Wt11 : (which == 1) ? Wt12 : (which == 2) ? Wt21 : Wt22;
        int K = (which & 1) ? 256 : 128;
        int N = (which & 1) ? 128 : 256;
        int k = idx / N, n = idx - k * N;
        Wt[n * K + k] = f2b(W[idx]);
    } else if (bid < NSB + 536) {
        int idx = (bid - NSB - 512) * 256 + tid;     // 6144 = 48*128
        int n = idx >> 7, k = idx & 127;
        Wfct[idx] = (n < 40) ? f2b(Wfc[k * 40 + n]) : (unsigned short)0;
    } else {
        int i = (bid - NSB - 536) * 256 + tid;       // 800000 groups of 8
        const float4 a = *reinterpret_cast<const float4*>(x + (size_t)i * 8);
        const float4 b = *reinterpret_cast<const float4*>(x + (size_t)i * 8 + 4);
        ushort4 u0, u1;
        u0.x = f2b(a.x); u0.y = f2b(a.y); u0.z = f2b(a.z); u0.w = f2b(a.w);
        u1.x = f2b(b.x); u1.y = f2b(b.y); u1.z = f2b(b.z); u1.w = f2b(b.w);
        *reinterpret_cast<ushort4*>(xb + (size_t)i * 8) = u0;
        *reinterpret_cast<ushort4*>(xb + (size_t)i * 8 + 4) = u1;
    }
}

// ---------------------------------------------------------------------------
// K1b: per-bucket scan over the 391 scatter-block counts -> global strip bases
// sbase[b*392 + k]; entry 391 = bucket total S_b (since padded count = 0).
// ---------------------------------------------------------------------------
__global__ __launch_bounds__(256) void scan_strips(
    const int* __restrict__ cnt, int* __restrict__ sbase) {
    __shared__ int ps[256];
    __shared__ int sc[512];
    const int b = blockIdx.x;
    const int tid = threadIdx.x;
    sc[tid] = (tid < NSB) ? cnt[b * NSB + tid] : 0;
    sc[tid + 256] = (tid + 256 < NSB) ? cnt[b * NSB + tid + 256] : 0;
    __syncthreads();
    const int c0 = sc[2 * tid], c1 = sc[2 * tid + 1];
    ps[tid] = c0 + c1;
    __syncthreads();
    for (int off = 1; off < 256; off <<= 1) {
        int u = (tid >= off) ? ps[tid - off] : 0;
        __syncthreads();
        ps[tid] += u;
        __syncthreads();
    }
    if (tid < 196) {
        const int off0 = ps[tid] - (c0 + c1);
        sbase[b * 392 + 2 * tid] = off0;
        sbase[b * 392 + 2 * tid + 1] = off0 + c0;   // index 391 == S_b
    }
}

// ---------------------------------------------------------------------------
// K1c: scatter pass 2 — place edges into COMPACTED per-bucket buffers using
// LDS cursors initialized from sbase (no global atomics; block-reserved runs).
// bufc entry: src | dloc<<16 (dloc = dst & 127).
// ---------------------------------------------------------------------------
__global__ __launch_bounds__(256) void place_compact(
    const int* __restrict__ srcv, const int* __restrict__ dstv,
    const int* __restrict__ sbase, int* __restrict__ bufc) {
    __shared__ int cur[NBUCK];
    const int k = blockIdx.x;
    const int tid = threadIdx.x;
    for (int i = tid; i < NBUCK; i += 256) cur[i] = sbase[i * 392 + k];
    __syncthreads();
    const int e0 = k * EPB;
#pragma unroll
    for (int j = 0; j < EPB / 256; ++j) {
        int e = e0 + j * 256 + tid;
        if (e < N_EDGES) {
            int d = dstv[e];
            int b = d >> 7;
            int pos = atomicAdd(&cur[b], 1);
            bufc[b * CAPB + pos] = srcv[e] | ((d & 127) << 16);
        }
    }
}

// ---------------------------------------------------------------------------
// K2: per-bucket finish — node hist from compacted input (flat, parallel),
// 128-wide scan -> row_ptr (129-stride), place into e_src. No strip walks.
// ---------------------------------------------------------------------------
__global__ __launch_bounds__(256) void finish_buckets(
    const int* __restrict__ sbase, const int* __restrict__ bufc,
    int* __restrict__ e_src, int* __restrict__ row_ptr) {
    __shared__ int nc[128];
    __shared__ int ps[128];
    const int b = blockIdx.x;
    const int tid = threadIdx.x;
    const int S = sbase[b * 392 + 391];
    const int gb = b * CAPB;
    if (tid < 128) nc[tid] = 0;
    __syncthreads();
    for (int t = tid; t < S; t += 256)
        atomicAdd(&nc[(bufc[gb + t] >> 16) & 127], 1);
    __syncthreads();
    if (tid < 128) ps[tid] = nc[tid];
    __syncthreads();
    for (int off = 1; off < 128; off <<= 1) {
        int u = (tid >= off && tid < 128) ? ps[tid - off] : 0;
        __syncthreads();
        if (tid < 128) ps[tid] += u;
        __syncthreads();
    }
    if (tid < 128) {
        const int excl = ps[tid] - nc[tid];
        row_ptr[b * 129 + tid] = gb + excl;
        nc[tid] = gb + excl;                 // absolute cursor
    }
    if (tid == 0) row_ptr[b * 129 + 128] = gb + S;
    __syncthreads();
    for (int t = tid; t < S; t += 256) {
        int p = bufc[gb + t];
        int pos = atomicAdd(&nc[(p >> 16) & 127], 1);
        e_src[pos] = p & 0xFFFF;
    }
}

// ---------------------------------------------------------------------------
// aggregate: agg[i] = x[i] + sum_{e in row i} x[e_src[e]]  — one wave/node.
// Quarter-wave split (16 lanes x ushort8 = 256B row), 4 edge streams/wave,
// unroll x4 -> 16 row-loads in flight. row_ptr is 129-strided per bucket.
// ---------------------------------------------------------------------------
__global__ __launch_bounds__(256) void agg_bf16q(const unsigned short* __restrict__ X,
                                                 const int* __restrict__ row_ptr,
                                                 const int* __restrict__ e_src,
                                                 unsigned short* __restrict__ agg) {
    const int node = (blockIdx.x * 256 + threadIdx.x) >> 6;
    const int lane = threadIdx.x & 63;
    const int qw = lane >> 4, ql = lane & 15;
    const size_t off = (size_t)ql * 8;

    const int rp = node + (node >> 7);
    const int beg = row_ptr[rp], end = row_ptr[rp + 1];
    float acc[8];
#pragma unroll
    for (int k = 0; k < 8; ++k) acc[k] = 0.f;

    if (qw == 0) {
        uint4 u = *reinterpret_cast<const uint4*>(X + (size_t)node * 128 + off);
        const unsigned int* up = (const unsigned int*)&u;
#pragma unroll
        for (int k = 0; k < 4; ++k) {
            acc[2 * k]     += ubits(up[k] << 16);
            acc[2 * k + 1] += ubits(up[k] & 0xFFFF0000u);
        }
    }

    int e = beg + qw;
    for (; e + 12 < end; e += 16) {
        const int s0 = e_src[e], s1 = e_src[e + 4], s2 = e_src[e + 8], s3 = e_src[e + 12];
        uint4 u0 = *reinterpret_cast<const uint4*>(X + (size_t)s0 * 128 + off);
        uint4 u1 = *reinterpret_cast<const uint4*>(X + (size_t)s1 * 128 + off);
        uint4 u2 = *reinterpret_cast<const uint4*>(X + (size_t)s2 * 128 + off);
        uint4 u3 = *reinterpret_cast<const uint4*>(X + (size_t)s3 * 128 + off);
        const unsigned int* p0 = (const unsigned int*)&u0;
        const unsigned int* p1 = (const unsigned int*)&u1;
        const unsigned int* p2 = (const unsigned int*)&u2;
        const unsigned int* p3 = (const unsigned int*)&u3;
#pragma unroll
        for (int k = 0; k < 4; ++k) {
            acc[2 * k]     += ubits(p0[k] << 16) + ubits(p1[k] << 16)
                            + ubits(p2[k] << 16) + ubits(p3[k] << 16);
            acc[2 * k + 1] += ubits(p0[k] & 0xFFFF0000u) + ubits(p1[k] & 0xFFFF0000u)
                            + ubits(p2[k] & 0xFFFF0000u) + ubits(p3[k] & 0xFFFF0000u);
        }
    }
    for (; e + 4 < end; e += 8) {
        const int s0 = e_src[e], s1 = e_src[e + 4];
        uint4 u0 = *reinterpret_cast<const uint4*>(X + (size_t)s0 * 128 + off);
        uint4 u1 = *reinterpret_cast<const uint4*>(X + (size_t)s1 * 128 + off);
        const unsigned int* p0 = (const unsigned int*)&u0;
        const unsigned int* p1 = (const unsigned int*)&u1;
#pragma unroll
        for (int k = 0; k < 4; ++k) {
            acc[2 * k]     += ubits(p0[k] << 16) + ubits(p1[k] << 16);
            acc[2 * k + 1] += ubits(p0[k] & 0xFFFF0000u) + ubits(p1[k] & 0xFFFF0000u);
        }
    }
    if (e < end) {
        const int s = e_src[e];
        uint4 u = *reinterpret_cast<const uint4*>(X + (size_t)s * 128 + off);
        const unsigned int* p = (const unsigned int*)&u;
#pragma unroll
        for (int k = 0; k < 4; ++k) {
            acc[2 * k]     += ubits(p[k] << 16);
            acc[2 * k + 1] += ubits(p[k] & 0xFFFF0000u);
        }
    }

#pragma unroll
    for (int k = 0; k < 8; ++k) acc[k] += __shfl_xor(acc[k], 32);
#pragma unroll
    for (int k = 0; k < 8; ++k) acc[k] += __shfl_xor(acc[k], 16);

    if (qw == 0) {
        ushort4 o0, o1;
        o0.x = f2b(acc[0]); o0.y = f2b(acc[1]); o0.z = f2b(acc[2]); o0.w = f2b(acc[3]);
        o1.x = f2b(acc[4]); o1.y = f2b(acc[5]); o1.z = f2b(acc[6]); o1.w = f2b(acc[7]);
        unsigned short* p = agg + (size_t)node * 128 + off;
        *reinterpret_cast<ushort4*>(p) = o0;
        *reinterpret_cast<ushort4*>(p + 4) = o1;
    }
}

// ---------------------------------------------------------------------------
// Fused MLP v2: Y = relu(relu(X@W1+b1)@W2+b2) for a 64-row strip.
// CHANGE (round 7): MFMA B-operands load DIRECTLY from global (weights are
// 64 KB, L2-hot, every block reads the same) — B1h/B2q LDS staging and their
// ~10 barrier drains deleted. A and T overlap in LDS (A dead before T write).
// Barriers: A-ready, A-dead, T-ready (+ 2/chunk for FUSE's Hc transpose).
// LDS: max(A[64][136]=17408, T[64][264]=33792) = 33792 (+Hc 5120 for FUSE)
// -> 4 blocks/CU (was 3 / 2).
// ---------------------------------------------------------------------------
template <bool FUSE>
__global__ __launch_bounds__(256, 4) void mlp_fused(
    const unsigned short* __restrict__ X, const unsigned short* __restrict__ Wt1,
    const float* __restrict__ b1, const unsigned short* __restrict__ Wt2,
    const float* __restrict__ b2, unsigned short* __restrict__ Y,
    const unsigned short* __restrict__ Wfct, const float* __restrict__ bfc,
    float* __restrict__ out, int M) {
    __shared__ __align__(16) char smem[FUSE ? 38912 : 33792];
    unsigned short* A  = (unsigned short*)smem;             // [64][136] stage 1
    unsigned short* T  = (unsigned short*)smem;             // [64][264] stage 2 (overlaps A)
    unsigned short* Hc = (unsigned short*)(smem + 33792);   // [64][40]  FUSE only

    const int tid = threadIdx.x;
    const int m0 = blockIdx.x * 64;
    const int lane = tid & 63, w = tid >> 6;
    const int qm = lane & 15, quad = lane >> 4;

    // ---- load A (64 x 128 bf16) ----
#pragma unroll
    for (int j = 0; j < 4; ++j) {
        int i = j * 256 + tid;
        int r = i >> 4, c8 = (i & 15) << 3;
        uint4 v = {0, 0, 0, 0};
        if (m0 + r < M) v = *reinterpret_cast<const uint4*>(X + (size_t)(m0 + r) * 128 + c8);
        *reinterpret_cast<uint4*>(&A[r * 136 + c8]) = v;
    }
    __syncthreads();   // A ready

    // ---- stage 1: t[64][256] = relu(A @ W1 + b1), B-frags from global ----
    floatx4 acc1[2][4][2];
#pragma unroll
    for (int c = 0; c < 2; ++c)
#pragma unroll
        for (int mt = 0; mt < 4; ++mt)
#pragma unroll
            for (int nt = 0; nt < 2; ++nt) acc1[c][mt][nt] = {0.f, 0.f, 0.f, 0.f};

#pragma unroll
    for (int c = 0; c < 2; ++c) {
#pragma unroll
        for (int ks = 0; ks < 4; ++ks) {
            const int kb = ks * 32 + quad * 8;
            short8 a[4], b[2];
#pragma unroll
            for (int mt = 0; mt < 4; ++mt)
                a[mt] = *reinterpret_cast<const short8*>(&A[(mt * 16 + qm) * 136 + kb]);
#pragma unroll
            for (int nt = 0; nt < 2; ++nt)
                b[nt] = *reinterpret_cast<const short8*>(
                    Wt1 + (size_t)(c * 128 + w * 32 + nt * 16 + qm) * 128 + kb);
#pragma unroll
            for (int mt = 0; mt < 4; ++mt)
#pragma unroll
                for (int nt = 0; nt < 2; ++nt)
                    acc1[c][mt][nt] = __builtin_amdgcn_mfma_f32_16x16x32_bf16(
                        a[mt], b[nt], acc1[c][mt][nt], 0, 0, 0);
        }
    }
    __syncthreads();   // A dead — T may overwrite

    // ---- epilogue 1: T (bf16, LDS) = relu(acc1 + b1) ----
#pragma unroll
    for (int c = 0; c < 2; ++c) {
#pragma unroll
        for (int nt = 0; nt < 2; ++nt) {
            const int jcol = c * 128 + w * 32 + nt * 16 + qm;
            const float bj = b1[jcol];
#pragma unroll
            for (int mt = 0; mt < 4; ++mt)
#pragma unroll
                for (int r = 0; r < 4; ++r)
                    T[(mt * 16 + quad * 4 + r) * 264 + jcol] =
                        f2b(fmaxf(acc1[c][mt][nt][r] + bj, 0.f));
        }
    }
    __syncthreads();   // T ready

    // ---- stage 2: h = relu(T @ W2 + b2), B-frags from global ----
    floatx4 cacc[3];
#pragma unroll
    for (int nt = 0; nt < 3; ++nt) cacc[nt] = {0.f, 0.f, 0.f, 0.f};

#pragma unroll
    for (int c2 = 0; c2 < 4; ++c2) {
        floatx4 acc2[2];
        acc2[0] = {0.f, 0.f, 0.f, 0.f};
        acc2[1] = {0.f, 0.f, 0.f, 0.f};
#pragma unroll
        for (int ks = 0; ks < 8; ++ks) {
            const int kb = ks * 32 + quad * 8;
            short8 t0 = *reinterpret_cast<const short8*>(&T[((w & 1) * 32 + qm) * 264 + kb]);
            short8 t1 = *reinterpret_cast<const short8*>(&T[((w & 1) * 32 + 16 + qm) * 264 + kb]);
            short8 bb = *reinterpret_cast<const short8*>(
                Wt2 + (size_t)(c2 * 32 + (w >> 1) * 16 + qm) * 256 + kb);
            acc2[0] = __builtin_amdgcn_mfma_f32_16x16x32_bf16(t0, bb, acc2[0], 0, 0, 0);
            acc2[1] = __builtin_amdgcn_mfma_f32_16x16x32_bf16(t1, bb, acc2[1], 0, 0, 0);
        }

        const int ncol = c2 * 32 + (w >> 1) * 16 + qm;   // global h col
        const float bj = b2[ncol];
        if (!FUSE) {
#pragma unroll
            for (int mt2 = 0; mt2 < 2; ++mt2)
#pragma unroll
                for (int r = 0; r < 4; ++r) {
                    int row = m0 + (w & 1) * 32 + mt2 * 16 + quad * 4 + r;
                    if (row < M)
                        Y[(size_t)row * 128 + ncol] = f2b(fmaxf(acc2[mt2][r] + bj, 0.f));
                }
        } else {
            const int lcol = (w >> 1) * 16 + qm;
#pragma unroll
            for (int mt2 = 0; mt2 < 2; ++mt2)
#pragma unroll
                for (int r = 0; r < 4; ++r)
                    Hc[((w & 1) * 32 + mt2 * 16 + quad * 4 + r) * 40 + lcol] =
                        f2b(fmaxf(acc2[mt2][r] + bj, 0.f));
            __syncthreads();   // Hc ready
            // classifier partial: out += h[:, c2*32:+32] @ Wfct[:, c2*32:+32]^T
            short8 hf = *reinterpret_cast<const short8*>(&Hc[(w * 16 + qm) * 40 + quad * 8]);
#pragma unroll
            for (int nt = 0; nt < 3; ++nt) {
                short8 bf = *reinterpret_cast<const short8*>(
                    Wfct + (nt * 16 + qm) * 128 + c2 * 32 + quad * 8);
                cacc[nt] = __builtin_amdgcn_mfma_f32_16x16x32_bf16(hf, bf, cacc[nt], 0, 0, 0);
            }
            __syncthreads();   // Hc reusable
        }
    }

    if (FUSE) {
#pragma unroll
        for (int nt = 0; nt < 3; ++nt) {
            int col = nt * 16 + qm;
            if (col < 40) {
                const float bj = bfc[col];
#pragma unroll
                for (int r = 0; r < 4; ++r) {
                    int row = m0 + w * 16 + quad * 4 + r;
                    if (row < M) out[(size_t)row * 40 + col] = cacc[nt][r] + bj;
                }
            }
        }
    }
}

// ---------------------------------------------------------------------------
extern "C" void kernel_launch(void* const* d_in, const int* in_sizes, int n_in,
                              void* d_out, int out_size, void* d_ws, size_t ws_size,
                              hipStream_t stream) {
    const float* x   = (const float*)d_in[0];
    const int*   ei  = (const int*)d_in[1];
    const float* W11 = (const float*)d_in[2];
    const float* b11 = (const float*)d_in[3];
    const float* W12 = (const float*)d_in[4];
    const float* b12 = (const float*)d_in[5];
    const float* W21 = (const float*)d_in[6];
    const float* b21 = (const float*)d_in[7];
    const float* W22 = (const float*)d_in[8];
    const float* b22 = (const float*)d_in[9];
    const float* Wfc = (const float*)d_in[10];
    const float* bfc = (const float*)d_in[11];
    float* out = (float*)d_out;

    const int* srcv = ei;
    const int* dstv = ei + N_EDGES;

    unsigned short* agg  = (unsigned short*)d_ws;               // 50000*128 bf16
    unsigned short* h    = agg + (size_t)N_NODES * 128;
    unsigned short* xb   = h   + (size_t)N_NODES * 128;
    unsigned short* Wt11 = xb  + (size_t)N_NODES * 128;
    unsigned short* Wt12 = Wt11 + 256 * 128;
    unsigned short* Wt21 = Wt12 + 256 * 128;
    unsigned short* Wt22 = Wt21 + 256 * 128;
    unsigned short* Wfct = Wt22 + 256 * 128;                    // 48*128
    int* cnt     = (int*)(Wfct + 48 * 128);                     // 392*391 (pad 153664)
    int* sbase   = cnt + 153664;                                // 392*392
    int* row_ptr = sbase + 153664;                              // 392*129 (pad 50688)
    int* e_src   = row_ptr + 50688;                             // 392*2560
    int* bufc    = e_src + (size_t)NBUCK * CAPB;                // 392*2560

    // ---- K1a: per-(block,bucket) hist + all conversions ----
    hist_conv<<<NSB + 3661, 256, 0, stream>>>(
        dstv, x, W11, W12, W21, W22, Wfc,
        cnt, xb, Wt11, Wt12, Wt21, Wt22, Wfct);

    // ---- K1b: globalize strip bases (per-bucket scan over 391 blocks) ----
    scan_strips<<<NBUCK, 256, 0, stream>>>(cnt, sbase);

    // ---- K1c: compacted placement (plain stores into reserved runs) ----
    place_compact<<<NSB, 256, 0, stream>>>(srcv, dstv, sbase, bufc);

    // ---- K2: per-bucket finish: hist/scan/place from contiguous input ----
    finish_buckets<<<NBUCK, 256, 0, stream>>>(sbase, bufc, e_src, row_ptr);

    const int agg_blocks = N_NODES * 64 / 256;        // 12500, one wave per node
    const int mlp_blocks = (N_NODES + 63) / 64;       // 782

    // ---- layer 1 ----
    agg_bf16q<<<agg_blocks, 256, 0, stream>>>(xb, row_ptr, e_src, agg);
    mlp_fused<false><<<mlp_blocks, 256, 0, stream>>>(
        agg, Wt11, b11, Wt12, b12, h, nullptr, nullptr, nullptr, N_NODES);
    // ---- layer 2 + classifier ----
    agg_bf16q<<<agg_blocks, 256, 0, stream>>>(h, row_ptr, e_src, agg);
    mlp_fused<true><<<mlp_blocks, 256, 0, stream>>>(
        agg, Wt21, b21, Wt22, b22, nullptr, Wfct, bfc, out, N_NODES);
}

// Round 8
// 232.648 us; speedup vs baseline: 1.0496x; 1.0496x over previous
//
#include <hip/hip_runtime.h>

#define N_NODES 50000
#define N_EDGES 800000
#define NBUCK   392           // buckets of 128 nodes (dst >> 7)
#define EPB     2048          // edges per scatter block
#define NSB     391           // scatter blocks = ceil(800000/2048)
#define CAPB    2560          // per-bucket capacity (mean ~2041, +11 sigma)

typedef __attribute__((ext_vector_type(8))) short short8;
typedef __attribute__((ext_vector_type(4))) float floatx4;

__device__ __forceinline__ float ubits(unsigned int b) {
    union { unsigned int i; float f; } v;
    v.i = b;
    return v.f;
}
__device__ __forceinline__ unsigned short f2b(float f) {  // round-nearest-even
    union { float f; unsigned int i; } v;
    v.f = f;
    unsigned int r = v.i + 0x7FFFu + ((v.i >> 16) & 1u);
    return (unsigned short)(r >> 16);
}

// ---------------------------------------------------------------------------
// K1a: per-(block,bucket) histogram (LDS, no global atomics) + x->bf16.
// [0,391): hist block k -> cnt[b*391+k].  [391,3516): x -> bf16.
// (weight conversions moved to scan_conv — they cover the scan's idle CUs)
// ---------------------------------------------------------------------------
__global__ __launch_bounds__(256) void hist_conv(
    const int* __restrict__ dstv, const float* __restrict__ x,
    int* __restrict__ cnt, unsigned short* __restrict__ xb) {
    const int bid = blockIdx.x;
    const int tid = threadIdx.x;
    if (bid < NSB) {
        __shared__ int hist[NBUCK];
        const int k = bid;
        const int e0 = k * EPB;
        for (int i = tid; i < NBUCK; i += 256) hist[i] = 0;
        __syncthreads();
#pragma unroll
        for (int j = 0; j < EPB / 256; ++j) {
            int e = e0 + j * 256 + tid;
            if (e < N_EDGES) atomicAdd(&hist[dstv[e] >> 7], 1);
        }
        __syncthreads();
        for (int i = tid; i < NBUCK; i += 256) cnt[i * NSB + k] = hist[i];
    } else {
        int i = (bid - NSB) * 256 + tid;             // 800000 groups of 8
        const float4 a = *reinterpret_cast<const float4*>(x + (size_t)i * 8);
        const float4 b = *reinterpret_cast<const float4*>(x + (size_t)i * 8 + 4);
        ushort4 u0, u1;
        u0.x = f2b(a.x); u0.y = f2b(a.y); u0.z = f2b(a.z); u0.w = f2b(a.w);
        u1.x = f2b(b.x); u1.y = f2b(b.y); u1.z = f2b(b.z); u1.w = f2b(b.w);
        *reinterpret_cast<ushort4*>(xb + (size_t)i * 8) = u0;
        *reinterpret_cast<ushort4*>(xb + (size_t)i * 8 + 4) = u1;
    }
}

// ---------------------------------------------------------------------------
// K1b: per-bucket scan over the 391 scatter-block counts -> global strip bases
// sbase[b*392 + k]; entry 391 = bucket total S_b.  Weight conversions packed
// behind the 392 scan blocks as cover.
// [0,392): scan.  [392,904): weights.  [904,928): Wfct.
// ---------------------------------------------------------------------------
__global__ __launch_bounds__(256) void scan_conv(
    const int* __restrict__ cnt, int* __restrict__ sbase,
    const float* __restrict__ W11, const float* __restrict__ W12,
    const float* __restrict__ W21, const float* __restrict__ W22,
    const float* __restrict__ Wfc,
    unsigned short* __restrict__ Wt11, unsigned short* __restrict__ Wt12,
    unsigned short* __restrict__ Wt21, unsigned short* __restrict__ Wt22,
    unsigned short* __restrict__ Wfct) {
    const int bid = blockIdx.x;
    const int tid = threadIdx.x;
    if (bid < NBUCK) {
        __shared__ int ps[256];
        __shared__ int sc[512];
        const int b = bid;
        sc[tid] = (tid < NSB) ? cnt[b * NSB + tid] : 0;
        sc[tid + 256] = (tid + 256 < NSB) ? cnt[b * NSB + tid + 256] : 0;
        __syncthreads();
        const int c0 = sc[2 * tid], c1 = sc[2 * tid + 1];
        ps[tid] = c0 + c1;
        __syncthreads();
        for (int off = 1; off < 256; off <<= 1) {
            int u = (tid >= off) ? ps[tid - off] : 0;
            __syncthreads();
            ps[tid] += u;
            __syncthreads();
        }
        if (tid < 196) {
            const int off0 = ps[tid] - (c0 + c1);
            sbase[b * 392 + 2 * tid] = off0;
            sbase[b * 392 + 2 * tid + 1] = off0 + c0;   // index 391 == S_b
        }
    } else if (bid < NBUCK + 512) {
        int wb = bid - NBUCK;
        int which = wb >> 7;
        int idx = (wb & 127) * 256 + tid;
        const float* W = (which == 0) ? W11 : (which == 1) ? W12 : (which == 2) ? W21 : W22;
        unsigned short* Wt = (which == 0) ? Wt11 : (which == 1) ? Wt12 : (which == 2) ? Wt21 : Wt22;
        int K = (which & 1) ? 256 : 128;
        int N = (which & 1) ? 128 : 256;
        int k = idx / N, n = idx - k * N;
        Wt[n * K + k] = f2b(W[idx]);
    } else {
        int idx = (bid - NBUCK - 512) * 256 + tid;   // 6144 = 48*128
        int n = idx >> 7, k = idx & 127;
        Wfct[idx] = (n < 40) ? f2b(Wfc[k * 40 + n]) : (unsigned short)0;
    }
}

// ---------------------------------------------------------------------------
// K1c: scatter pass 2 — place edges into COMPACTED per-bucket buffers using
// LDS cursors initialized from sbase (no global atomics; block-reserved runs).
// bufc entry: src | dloc<<16 (dloc = dst & 127).
// ---------------------------------------------------------------------------
__global__ __launch_bounds__(256) void place_compact(
    const int* __restrict__ srcv, const int* __restrict__ dstv,
    const int* __restrict__ sbase, int* __restrict__ bufc) {
    __shared__ int cur[NBUCK];
    const int k = blockIdx.x;
    const int tid = threadIdx.x;
    for (int i = tid; i < NBUCK; i += 256) cur[i] = sbase[i * 392 + k];
    __syncthreads();
    const int e0 = k * EPB;
#pragma unroll
    for (int j = 0; j < EPB / 256; ++j) {
        int e = e0 + j * 256 + tid;
        if (e < N_EDGES) {
            int d = dstv[e];
            int b = d >> 7;
            int pos = atomicAdd(&cur[b], 1);
            bufc[b * CAPB + pos] = srcv[e] | ((d & 127) << 16);
        }
    }
}

// ---------------------------------------------------------------------------
// K2: per-bucket finish — node hist from compacted input (flat, parallel),
// 128-wide scan -> row_ptr (129-stride), place into e_src. No strip walks.
// ---------------------------------------------------------------------------
__global__ __launch_bounds__(256) void finish_buckets(
    const int* __restrict__ sbase, const int* __restrict__ bufc,
    int* __restrict__ e_src, int* __restrict__ row_ptr) {
    __shared__ int nc[128];
    __shared__ int ps[128];
    const int b = blockIdx.x;
    const int tid = threadIdx.x;
    const int S = sbase[b * 392 + 391];
    const int gb = b * CAPB;
    if (tid < 128) nc[tid] = 0;
    __syncthreads();
    for (int t = tid; t < S; t += 256)
        atomicAdd(&nc[(bufc[gb + t] >> 16) & 127], 1);
    __syncthreads();
    if (tid < 128) ps[tid] = nc[tid];
    __syncthreads();
    for (int off = 1; off < 128; off <<= 1) {
        int u = (tid >= off && tid < 128) ? ps[tid - off] : 0;
        __syncthreads();
        if (tid < 128) ps[tid] += u;
        __syncthreads();
    }
    if (tid < 128) {
        const int excl = ps[tid] - nc[tid];
        row_ptr[b * 129 + tid] = gb + excl;
        nc[tid] = gb + excl;                 // absolute cursor
    }
    if (tid == 0) row_ptr[b * 129 + 128] = gb + S;
    __syncthreads();
    for (int t = tid; t < S; t += 256) {
        int p = bufc[gb + t];
        int pos = atomicAdd(&nc[(p >> 16) & 127], 1);
        e_src[pos] = p & 0xFFFF;
    }
}

// ---------------------------------------------------------------------------
// aggregate: agg[i] = x[i] + sum_{e in row i} x[e_src[e]]  — one wave/node.
// Quarter-wave split (16 lanes x ushort8 = 256B row), 4 edge streams/wave,
// unroll x4 -> 16 row-loads in flight. row_ptr is 129-strided per bucket.
// ---------------------------------------------------------------------------
__global__ __launch_bounds__(256) void agg_bf16q(const unsigned short* __restrict__ X,
                                                 const int* __restrict__ row_ptr,
                                                 const int* __restrict__ e_src,
                                                 unsigned short* __restrict__ agg) {
    const int node = (blockIdx.x * 256 + threadIdx.x) >> 6;
    const int lane = threadIdx.x & 63;
    const int qw = lane >> 4, ql = lane & 15;
    const size_t off = (size_t)ql * 8;

    const int rp = node + (node >> 7);
    const int beg = row_ptr[rp], end = row_ptr[rp + 1];
    float acc[8];
#pragma unroll
    for (int k = 0; k < 8; ++k) acc[k] = 0.f;

    if (qw == 0) {
        uint4 u = *reinterpret_cast<const uint4*>(X + (size_t)node * 128 + off);
        const unsigned int* up = (const unsigned int*)&u;
#pragma unroll
        for (int k = 0; k < 4; ++k) {
            acc[2 * k]     += ubits(up[k] << 16);
            acc[2 * k + 1] += ubits(up[k] & 0xFFFF0000u);
        }
    }

    int e = beg + qw;
    for (; e + 12 < end; e += 16) {
        const int s0 = e_src[e], s1 = e_src[e + 4], s2 = e_src[e + 8], s3 = e_src[e + 12];
        uint4 u0 = *reinterpret_cast<const uint4*>(X + (size_t)s0 * 128 + off);
        uint4 u1 = *reinterpret_cast<const uint4*>(X + (size_t)s1 * 128 + off);
        uint4 u2 = *reinterpret_cast<const uint4*>(X + (size_t)s2 * 128 + off);
        uint4 u3 = *reinterpret_cast<const uint4*>(X + (size_t)s3 * 128 + off);
        const unsigned int* p0 = (const unsigned int*)&u0;
        const unsigned int* p1 = (const unsigned int*)&u1;
        const unsigned int* p2 = (const unsigned int*)&u2;
        const unsigned int* p3 = (const unsigned int*)&u3;
#pragma unroll
        for (int k = 0; k < 4; ++k) {
            acc[2 * k]     += ubits(p0[k] << 16) + ubits(p1[k] << 16)
                            + ubits(p2[k] << 16) + ubits(p3[k] << 16);
            acc[2 * k + 1] += ubits(p0[k] & 0xFFFF0000u) + ubits(p1[k] & 0xFFFF0000u)
                            + ubits(p2[k] & 0xFFFF0000u) + ubits(p3[k] & 0xFFFF0000u);
        }
    }
    for (; e + 4 < end; e += 8) {
        const int s0 = e_src[e], s1 = e_src[e + 4];
        uint4 u0 = *reinterpret_cast<const uint4*>(X + (size_t)s0 * 128 + off);
        uint4 u1 = *reinterpret_cast<const uint4*>(X + (size_t)s1 * 128 + off);
        const unsigned int* p0 = (const unsigned int*)&u0;
        const unsigned int* p1 = (const unsigned int*)&u1;
#pragma unroll
        for (int k = 0; k < 4; ++k) {
            acc[2 * k]     += ubits(p0[k] << 16) + ubits(p1[k] << 16);
            acc[2 * k + 1] += ubits(p0[k] & 0xFFFF0000u) + ubits(p1[k] & 0xFFFF0000u);
        }
    }
    if (e < end) {
        const int s = e_src[e];
        uint4 u = *reinterpret_cast<const uint4*>(X + (size_t)s * 128 + off);
        const unsigned int* p = (const unsigned int*)&u;
#pragma unroll
        for (int k = 0; k < 4; ++k) {
            acc[2 * k]     += ubits(p[k] << 16);
            acc[2 * k + 1] += ubits(p[k] & 0xFFFF0000u);
        }
    }

#pragma unroll
    for (int k = 0; k < 8; ++k) acc[k] += __shfl_xor(acc[k], 32);
#pragma unroll
    for (int k = 0; k < 8; ++k) acc[k] += __shfl_xor(acc[k], 16);

    if (qw == 0) {
        ushort4 o0, o1;
        o0.x = f2b(acc[0]); o0.y = f2b(acc[1]); o0.z = f2b(acc[2]); o0.w = f2b(acc[3]);
        o1.x = f2b(acc[4]); o1.y = f2b(acc[5]); o1.z = f2b(acc[6]); o1.w = f2b(acc[7]);
        unsigned short* p = agg + (size_t)node * 128 + off;
        *reinterpret_cast<ushort4*>(p) = o0;
        *reinterpret_cast<ushort4*>(p + 4) = o1;
    }
}

// ---------------------------------------------------------------------------
// Fused MLP (round-6 structure, LDS-staged weights — round-7's global-B
// loads regressed 13 µs by exposing L2 latency inside the MFMA chain).
// FUSE change (round 8): accumulate full h[64][136] in LDS; classifier runs
// ONCE after the c2 loop (saves 8 barriers vs per-chunk Hc transpose).
// LDS layout (bytes):
//   [0,     17408): A[64][136]      | stage2: B2q[32][264] (16896)
//   [17408, 52224): B1h[128][136]   | stage2: T[64][264]   (33792, ends 51200)
//   [52224, 69632): Hf[64][136]     (FUSE only, full h tile)
// ---------------------------------------------------------------------------
template <bool FUSE>
__global__ __launch_bounds__(256, FUSE ? 2 : 3) void mlp_fused(
    const unsigned short* __restrict__ X, const unsigned short* __restrict__ Wt1,
    const float* __restrict__ b1, const unsigned short* __restrict__ Wt2,
    const float* __restrict__ b2, unsigned short* __restrict__ Y,
    const unsigned short* __restrict__ Wfct, const float* __restrict__ bfc,
    float* __restrict__ out, int M) {
    __shared__ __align__(16) char smem[FUSE ? 69632 : 52224];
    unsigned short* A   = (unsigned short*)smem;             // [64][136]
    unsigned short* B2q = (unsigned short*)smem;             // [32][264]
    unsigned short* B1h = (unsigned short*)(smem + 17408);   // [128][136]
    unsigned short* T   = (unsigned short*)(smem + 17408);   // [64][264]
    unsigned short* Hf  = (unsigned short*)(smem + 52224);   // [64][136] FUSE

    const int tid = threadIdx.x;
    const int m0 = blockIdx.x * 64;
    const int lane = tid & 63, w = tid >> 6;
    const int qm = lane & 15, quad = lane >> 4;

    // ---- load A (64 x 128 bf16) ----
#pragma unroll
    for (int j = 0; j < 4; ++j) {
        int i = j * 256 + tid;
        int r = i >> 4, c8 = (i & 15) << 3;
        uint4 v = {0, 0, 0, 0};
        if (m0 + r < M) v = *reinterpret_cast<const uint4*>(X + (size_t)(m0 + r) * 128 + c8);
        *reinterpret_cast<uint4*>(&A[r * 136 + c8]) = v;
    }

    // ---- stage 1: t[64][256] = relu(A @ W1 + b1), acc in VGPRs ----
    floatx4 acc1[2][4][2];
#pragma unroll
    for (int c = 0; c < 2; ++c)
#pragma unroll
        for (int mt = 0; mt < 4; ++mt)
#pragma unroll
            for (int nt = 0; nt < 2; ++nt) acc1[c][mt][nt] = {0.f, 0.f, 0.f, 0.f};

    for (int c = 0; c < 2; ++c) {
#pragma unroll
        for (int j = 0; j < 8; ++j) {
            int i = j * 256 + tid;
            int r = i >> 4, c8 = (i & 15) << 3;
            *reinterpret_cast<uint4*>(&B1h[r * 136 + c8]) =
                *reinterpret_cast<const uint4*>(Wt1 + (size_t)(c * 128 + r) * 128 + c8);
        }
        __syncthreads();
#pragma unroll
        for (int ks = 0; ks < 4; ++ks) {
            const int kb = ks * 32 + quad * 8;
            short8 a[4], b[2];
#pragma unroll
            for (int mt = 0; mt < 4; ++mt)
                a[mt] = *reinterpret_cast<const short8*>(&A[(mt * 16 + qm) * 136 + kb]);
#pragma unroll
            for (int nt = 0; nt < 2; ++nt)
                b[nt] = *reinterpret_cast<const short8*>(&B1h[(w * 32 + nt * 16 + qm) * 136 + kb]);
#pragma unroll
            for (int mt = 0; mt < 4; ++mt)
#pragma unroll
                for (int nt = 0; nt < 2; ++nt)
                    acc1[c][mt][nt] = __builtin_amdgcn_mfma_f32_16x16x32_bf16(
                        a[mt], b[nt], acc1[c][mt][nt], 0, 0, 0);
        }
        __syncthreads();
    }

    // ---- epilogue 1: T (bf16, LDS) = relu(acc1 + b1) ----
#pragma unroll
    for (int c = 0; c < 2; ++c) {
#pragma unroll
        for (int nt = 0; nt < 2; ++nt) {
            const int jcol = c * 128 + w * 32 + nt * 16 + qm;
            const float bj = b1[jcol];
#pragma unroll
            for (int mt = 0; mt < 4; ++mt)
#pragma unroll
                for (int r = 0; r < 4; ++r)
                    T[(mt * 16 + quad * 4 + r) * 264 + jcol] =
                        f2b(fmaxf(acc1[c][mt][nt][r] + bj, 0.f));
        }
    }

    // ---- stage 2: h = relu(T @ W2 + b2), W2 streamed in 4x32-row chunks ----
    for (int c2 = 0; c2 < 4; ++c2) {
#pragma unroll
        for (int j = 0; j < 4; ++j) {
            int i = j * 256 + tid;
            int r = i >> 5, c8 = (i & 31) << 3;
            *reinterpret_cast<uint4*>(&B2q[r * 264 + c8]) =
                *reinterpret_cast<const uint4*>(Wt2 + (size_t)(c2 * 32 + r) * 256 + c8);
        }
        __syncthreads();

        floatx4 acc2[2];
        acc2[0] = {0.f, 0.f, 0.f, 0.f};
        acc2[1] = {0.f, 0.f, 0.f, 0.f};
#pragma unroll
        for (int ks = 0; ks < 8; ++ks) {
            const int kb = ks * 32 + quad * 8;
            short8 t0 = *reinterpret_cast<const short8*>(&T[((w & 1) * 32 + qm) * 264 + kb]);
            short8 t1 = *reinterpret_cast<const short8*>(&T[((w & 1) * 32 + 16 + qm) * 264 + kb]);
            short8 bb = *reinterpret_cast<const short8*>(&B2q[((w >> 1) * 16 + qm) * 264 + kb]);
            acc2[0] = __builtin_amdgcn_mfma_f32_16x16x32_bf16(t0, bb, acc2[0], 0, 0, 0);
            acc2[1] = __builtin_amdgcn_mfma_f32_16x16x32_bf16(t1, bb, acc2[1], 0, 0, 0);
        }

        const int ncol = c2 * 32 + (w >> 1) * 16 + qm;   // global h col
        const float bj = b2[ncol];
        if (!FUSE) {
#pragma unroll
            for (int mt2 = 0; mt2 < 2; ++mt2)
#pragma unroll
                for (int r = 0; r < 4; ++r) {
                    int row = m0 + (w & 1) * 32 + mt2 * 16 + quad * 4 + r;
                    if (row < M)
                        Y[(size_t)row * 128 + ncol] = f2b(fmaxf(acc2[mt2][r] + bj, 0.f));
                }
        } else {
            // write h slice into the full-tile Hf — no extra barrier needed;
            // the loop-end sync (B2q protection) also publishes these writes.
#pragma unroll
            for (int mt2 = 0; mt2 < 2; ++mt2)
#pragma unroll
                for (int r = 0; r < 4; ++r)
                    Hf[((w & 1) * 32 + mt2 * 16 + quad * 4 + r) * 136 + ncol] =
                        f2b(fmaxf(acc2[mt2][r] + bj, 0.f));
        }
        __syncthreads();
    }

    if (FUSE) {
        // ---- classifier: out = h @ Wfct^T + bfc, single pass over Hf ----
        floatx4 cacc[3];
#pragma unroll
        for (int nt = 0; nt < 3; ++nt) cacc[nt] = {0.f, 0.f, 0.f, 0.f};
#pragma unroll
        for (int c2 = 0; c2 < 4; ++c2) {
            short8 hf = *reinterpret_cast<const short8*>(
                &Hf[(w * 16 + qm) * 136 + c2 * 32 + quad * 8]);
#pragma unroll
            for (int nt = 0; nt < 3; ++nt) {
                short8 bf = *reinterpret_cast<const short8*>(
                    Wfct + (nt * 16 + qm) * 128 + c2 * 32 + quad * 8);
                cacc[nt] = __builtin_amdgcn_mfma_f32_16x16x32_bf16(hf, bf, cacc[nt], 0, 0, 0);
            }
        }
#pragma unroll
        for (int nt = 0; nt < 3; ++nt) {
            int col = nt * 16 + qm;
            if (col < 40) {
                const float bj = bfc[col];
#pragma unroll
                for (int r = 0; r < 4; ++r) {
                    int row = m0 + w * 16 + quad * 4 + r;
                    if (row < M) out[(size_t)row * 40 + col] = cacc[nt][r] + bj;
                }
            }
        }
    }
}

// ---------------------------------------------------------------------------
extern "C" void kernel_launch(void* const* d_in, const int* in_sizes, int n_in,
                              void* d_out, int out_size, void* d_ws, size_t ws_size,
                              hipStream_t stream) {
    const float* x   = (const float*)d_in[0];
    const int*   ei  = (const int*)d_in[1];
    const float* W11 = (const float*)d_in[2];
    const float* b11 = (const float*)d_in[3];
    const float* W12 = (const float*)d_in[4];
    const float* b12 = (const float*)d_in[5];
    const float* W21 = (const float*)d_in[6];
    const float* b21 = (const float*)d_in[7];
    const float* W22 = (const float*)d_in[8];
    const float* b22 = (const float*)d_in[9];
    const float* Wfc = (const float*)d_in[10];
    const float* bfc = (const float*)d_in[11];
    float* out = (float*)d_out;

    const int* srcv = ei;
    const int* dstv = ei + N_EDGES;

    unsigned short* agg  = (unsigned short*)d_ws;               // 50000*128 bf16
    unsigned short* h    = agg + (size_t)N_NODES * 128;
    unsigned short* xb   = h   + (size_t)N_NODES * 128;
    unsigned short* Wt11 = xb  + (size_t)N_NODES * 128;
    unsigned short* Wt12 = Wt11 + 256 * 128;
    unsigned short* Wt21 = Wt12 + 256 * 128;
    unsigned short* Wt22 = Wt21 + 256 * 128;
    unsigned short* Wfct = Wt22 + 256 * 128;                    // 48*128
    int* cnt     = (int*)(Wfct + 48 * 128);                     // 392*391 (pad 153664)
    int* sbase   = cnt + 153664;                                // 392*392
    int* row_ptr = sbase + 153664;                              // 392*129 (pad 50688)
    int* e_src   = row_ptr + 50688;                             // 392*2560
    int* bufc    = e_src + (size_t)NBUCK * CAPB;                // 392*2560

    // ---- K1a: per-(block,bucket) hist + x->bf16 ----
    hist_conv<<<NSB + 3125, 256, 0, stream>>>(dstv, x, cnt, xb);

    // ---- K1b: strip-base scan + weight conversions (cover) ----
    scan_conv<<<NBUCK + 536, 256, 0, stream>>>(
        cnt, sbase, W11, W12, W21, W22, Wfc,
        Wt11, Wt12, Wt21, Wt22, Wfct);

    // ---- K1c: compacted placement (plain stores into reserved runs) ----
    place_compact<<<NSB, 256, 0, stream>>>(srcv, dstv, sbase, bufc);

    // ---- K2: per-bucket finish: hist/scan/place from contiguous input ----
    finish_buckets<<<NBUCK, 256, 0, stream>>>(sbase, bufc, e_src, row_ptr);

    const int agg_blocks = N_NODES * 64 / 256;        // 12500, one wave per node
    const int mlp_blocks = (N_NODES + 63) / 64;       // 782

    // ---- layer 1 ----
    agg_bf16q<<<agg_blocks, 256, 0, stream>>>(xb, row_ptr, e_src, agg);
    mlp_fused<false><<<mlp_blocks, 256, 0, stream>>>(
        agg, Wt11, b11, Wt12, b12, h, nullptr, nullptr, nullptr, N_NODES);
    // ---- layer 2 + classifier ----
    agg_bf16q<<<agg_blocks, 256, 0, stream>>>(h, row_ptr, e_src, agg);
    mlp_fused<true><<<mlp_blocks, 256, 0, stream>>>(
        agg, Wt21, b21, Wt22, b22, nullptr, Wfct, bfc, out, N_NODES);
}

// Round 9
// 226.084 us; speedup vs baseline: 1.0801x; 1.0290x over previous
//
#include <hip/hip_runtime.h>

#define N_NODES 50000
#define N_EDGES 800000
#define NBUCK   392           // buckets of 128 nodes (dst >> 7)
#define EPB     2048          // edges per scatter block
#define NSB     391           // scatter blocks = ceil(800000/2048)
#define CAPB    2560          // per-bucket capacity (mean ~2041, +11 sigma)

typedef __attribute__((ext_vector_type(8))) short short8;
typedef __attribute__((ext_vector_type(4))) float floatx4;

__device__ __forceinline__ float ubits(unsigned int b) {
    union { unsigned int i; float f; } v;
    v.i = b;
    return v.f;
}
__device__ __forceinline__ unsigned short f2b(float f) {  // round-nearest-even
    union { float f; unsigned int i; } v;
    v.f = f;
    unsigned int r = v.i + 0x7FFFu + ((v.i >> 16) & 1u);
    return (unsigned short)(r >> 16);
}

// ---------------------------------------------------------------------------
// Fragment-order weight packs (round 9). The MLP holds weights in VGPRs;
// pack layout Wp[(v*256 + tid)*8 + j] makes the per-block register load
// fully coalesced (one 16B load per (v, tid)).
// stage-1 (K=128 -> N=256): v = c*8 + ks*2 + nt  (16 vectors/thread)
//   k = ks*32 + quad*8 + j, n = c*128 + w*32 + nt*16 + qm, src W[k*256+n]
// stage-2 (K=256 -> N=128): v2 = c2*8 + ks       (32 vectors/thread, 2x dup)
//   k = ks*32 + quad*8 + j, n = c2*32 + (w>>1)*16 + qm, src W[k*128+n]
// ---------------------------------------------------------------------------
__device__ __forceinline__ void pack_s1(const float* __restrict__ W,
                                        unsigned short* __restrict__ Wp,
                                        int blk, int tid) {
    int p = blk * 256 + tid;                 // [0, 32768)
    int j = p & 7, t2 = (p >> 3) & 255, v = p >> 11;
    int w = t2 >> 6, lane = t2 & 63, quad = lane >> 4, qm = lane & 15;
    int c = v >> 3, ks = (v >> 1) & 3, nt = v & 1;
    int k = ks * 32 + quad * 8 + j;
    int n = c * 128 + w * 32 + nt * 16 + qm;
    Wp[p] = f2b(W[k * 256 + n]);
}
__device__ __forceinline__ void pack_s2(const float* __restrict__ W,
                                        unsigned short* __restrict__ Wp,
                                        int blk, int tid) {
    int p = blk * 256 + tid;                 // [0, 65536)
    int j = p & 7, t2 = (p >> 3) & 255, v2 = p >> 11;
    int w = t2 >> 6, lane = t2 & 63, quad = lane >> 4, qm = lane & 15;
    int c2 = v2 >> 3, ks = v2 & 7;
    int k = ks * 32 + quad * 8 + j;
    int n = c2 * 32 + (w >> 1) * 16 + qm;
    Wp[p] = f2b(W[k * 128 + n]);
}

// ---------------------------------------------------------------------------
// K1a: per-(block,bucket) histogram (LDS, no global atomics) + x->bf16.
// [0,391): hist block k -> cnt[b*391+k].  [391,3516): x -> bf16.
// ---------------------------------------------------------------------------
__global__ __launch_bounds__(256) void hist_conv(
    const int* __restrict__ dstv, const float* __restrict__ x,
    int* __restrict__ cnt, unsigned short* __restrict__ xb) {
    const int bid = blockIdx.x;
    const int tid = threadIdx.x;
    if (bid < NSB) {
        __shared__ int hist[NBUCK];
        const int k = bid;
        const int e0 = k * EPB;
        for (int i = tid; i < NBUCK; i += 256) hist[i] = 0;
        __syncthreads();
#pragma unroll
        for (int j = 0; j < EPB / 256; ++j) {
            int e = e0 + j * 256 + tid;
            if (e < N_EDGES) atomicAdd(&hist[dstv[e] >> 7], 1);
        }
        __syncthreads();
        for (int i = tid; i < NBUCK; i += 256) cnt[i * NSB + k] = hist[i];
    } else {
        int i = (bid - NSB) * 256 + tid;             // 800000 groups of 8
        const float4 a = *reinterpret_cast<const float4*>(x + (size_t)i * 8);
        const float4 b = *reinterpret_cast<const float4*>(x + (size_t)i * 8 + 4);
        ushort4 u0, u1;
        u0.x = f2b(a.x); u0.y = f2b(a.y); u0.z = f2b(a.z); u0.w = f2b(a.w);
        u1.x = f2b(b.x); u1.y = f2b(b.y); u1.z = f2b(b.z); u1.w = f2b(b.w);
        *reinterpret_cast<ushort4*>(xb + (size_t)i * 8) = u0;
        *reinterpret_cast<ushort4*>(xb + (size_t)i * 8 + 4) = u1;
    }
}

// ---------------------------------------------------------------------------
// K1b: strip-base scan (392 blocks) + fragment-order weight packing as cover.
// [0,392): scan.  [392,520): W11 pack.  [520,776): W12 pack.
// [776,904): W21 pack.  [904,1160): W22 pack.  [1160,1184): Wfct.
// ---------------------------------------------------------------------------
__global__ __launch_bounds__(256) void scan_conv(
    const int* __restrict__ cnt, int* __restrict__ sbase,
    const float* __restrict__ W11, const float* __restrict__ W12,
    const float* __restrict__ W21, const float* __restrict__ W22,
    const float* __restrict__ Wfc,
    unsigned short* __restrict__ Wp11, unsigned short* __restrict__ Wp12,
    unsigned short* __restrict__ Wp21, unsigned short* __restrict__ Wp22,
    unsigned short* __restrict__ Wfct) {
    const int bid = blockIdx.x;
    const int tid = threadIdx.x;
    if (bid < NBUCK) {
        __shared__ int ps[256];
        __shared__ int sc[512];
        const int b = bid;
        sc[tid] = (tid < NSB) ? cnt[b * NSB + tid] : 0;
        sc[tid + 256] = (tid + 256 < NSB) ? cnt[b * NSB + tid + 256] : 0;
        __syncthreads();
        const int c0 = sc[2 * tid], c1 = sc[2 * tid + 1];
        ps[tid] = c0 + c1;
        __syncthreads();
        for (int off = 1; off < 256; off <<= 1) {
            int u = (tid >= off) ? ps[tid - off] : 0;
            __syncthreads();
            ps[tid] += u;
            __syncthreads();
        }
        if (tid < 196) {
            const int off0 = ps[tid] - (c0 + c1);
            sbase[b * 392 + 2 * tid] = off0;
            sbase[b * 392 + 2 * tid + 1] = off0 + c0;   // index 391 == S_b
        }
    } else if (bid < NBUCK + 128) {
        pack_s1(W11, Wp11, bid - NBUCK, tid);
    } else if (bid < NBUCK + 384) {
        pack_s2(W12, Wp12, bid - NBUCK - 128, tid);
    } else if (bid < NBUCK + 512) {
        pack_s1(W21, Wp21, bid - NBUCK - 384, tid);
    } else if (bid < NBUCK + 768) {
        pack_s2(W22, Wp22, bid - NBUCK - 512, tid);
    } else {
        int idx = (bid - NBUCK - 768) * 256 + tid;   // 6144 = 48*128
        int n = idx >> 7, k = idx & 127;
        Wfct[idx] = (n < 40) ? f2b(Wfc[k * 40 + n]) : (unsigned short)0;
    }
}

// ---------------------------------------------------------------------------
// K1c: scatter pass 2 — place edges into COMPACTED per-bucket buffers using
// LDS cursors initialized from sbase (no global atomics; block-reserved runs).
// ---------------------------------------------------------------------------
__global__ __launch_bounds__(256) void place_compact(
    const int* __restrict__ srcv, const int* __restrict__ dstv,
    const int* __restrict__ sbase, int* __restrict__ bufc) {
    __shared__ int cur[NBUCK];
    const int k = blockIdx.x;
    const int tid = threadIdx.x;
    for (int i = tid; i < NBUCK; i += 256) cur[i] = sbase[i * 392 + k];
    __syncthreads();
    const int e0 = k * EPB;
#pragma unroll
    for (int j = 0; j < EPB / 256; ++j) {
        int e = e0 + j * 256 + tid;
        if (e < N_EDGES) {
            int d = dstv[e];
            int b = d >> 7;
            int pos = atomicAdd(&cur[b], 1);
            bufc[b * CAPB + pos] = srcv[e] | ((d & 127) << 16);
        }
    }
}

// ---------------------------------------------------------------------------
// K2: per-bucket finish — node hist from compacted input (flat, parallel),
// 128-wide scan -> row_ptr (129-stride), place into e_src.
// ---------------------------------------------------------------------------
__global__ __launch_bounds__(256) void finish_buckets(
    const int* __restrict__ sbase, const int* __restrict__ bufc,
    int* __restrict__ e_src, int* __restrict__ row_ptr) {
    __shared__ int nc[128];
    __shared__ int ps[128];
    const int b = blockIdx.x;
    const int tid = threadIdx.x;
    const int S = sbase[b * 392 + 391];
    const int gb = b * CAPB;
    if (tid < 128) nc[tid] = 0;
    __syncthreads();
    for (int t = tid; t < S; t += 256)
        atomicAdd(&nc[(bufc[gb + t] >> 16) & 127], 1);
    __syncthreads();
    if (tid < 128) ps[tid] = nc[tid];
    __syncthreads();
    for (int off = 1; off < 128; off <<= 1) {
        int u = (tid >= off && tid < 128) ? ps[tid - off] : 0;
        __syncthreads();
        if (tid < 128) ps[tid] += u;
        __syncthreads();
    }
    if (tid < 128) {
        const int excl = ps[tid] - nc[tid];
        row_ptr[b * 129 + tid] = gb + excl;
        nc[tid] = gb + excl;                 // absolute cursor
    }
    if (tid == 0) row_ptr[b * 129 + 128] = gb + S;
    __syncthreads();
    for (int t = tid; t < S; t += 256) {
        int p = bufc[gb + t];
        int pos = atomicAdd(&nc[(p >> 16) & 127], 1);
        e_src[pos] = p & 0xFFFF;
    }
}

// ---------------------------------------------------------------------------
// aggregate: agg[i] = x[i] + sum_{e in row i} x[e_src[e]]  — one wave/node.
// Quarter-wave split (16 lanes x ushort8 = 256B row), 4 edge streams/wave,
// unroll x4 -> 16 row-loads in flight. row_ptr is 129-strided per bucket.
// ---------------------------------------------------------------------------
__global__ __launch_bounds__(256) void agg_bf16q(const unsigned short* __restrict__ X,
                                                 const int* __restrict__ row_ptr,
                                                 const int* __restrict__ e_src,
                                                 unsigned short* __restrict__ agg) {
    const int node = (blockIdx.x * 256 + threadIdx.x) >> 6;
    const int lane = threadIdx.x & 63;
    const int qw = lane >> 4, ql = lane & 15;
    const size_t off = (size_t)ql * 8;

    const int rp = node + (node >> 7);
    const int beg = row_ptr[rp], end = row_ptr[rp + 1];
    float acc[8];
#pragma unroll
    for (int k = 0; k < 8; ++k) acc[k] = 0.f;

    if (qw == 0) {
        uint4 u = *reinterpret_cast<const uint4*>(X + (size_t)node * 128 + off);
        const unsigned int* up = (const unsigned int*)&u;
#pragma unroll
        for (int k = 0; k < 4; ++k) {
            acc[2 * k]     += ubits(up[k] << 16);
            acc[2 * k + 1] += ubits(up[k] & 0xFFFF0000u);
        }
    }

    int e = beg + qw;
    for (; e + 12 < end; e += 16) {
        const int s0 = e_src[e], s1 = e_src[e + 4], s2 = e_src[e + 8], s3 = e_src[e + 12];
        uint4 u0 = *reinterpret_cast<const uint4*>(X + (size_t)s0 * 128 + off);
        uint4 u1 = *reinterpret_cast<const uint4*>(X + (size_t)s1 * 128 + off);
        uint4 u2 = *reinterpret_cast<const uint4*>(X + (size_t)s2 * 128 + off);
        uint4 u3 = *reinterpret_cast<const uint4*>(X + (size_t)s3 * 128 + off);
        const unsigned int* p0 = (const unsigned int*)&u0;
        const unsigned int* p1 = (const unsigned int*)&u1;
        const unsigned int* p2 = (const unsigned int*)&u2;
        const unsigned int* p3 = (const unsigned int*)&u3;
#pragma unroll
        for (int k = 0; k < 4; ++k) {
            acc[2 * k]     += ubits(p0[k] << 16) + ubits(p1[k] << 16)
                            + ubits(p2[k] << 16) + ubits(p3[k] << 16);
            acc[2 * k + 1] += ubits(p0[k] & 0xFFFF0000u) + ubits(p1[k] & 0xFFFF0000u)
                            + ubits(p2[k] & 0xFFFF0000u) + ubits(p3[k] & 0xFFFF0000u);
        }
    }
    for (; e + 4 < end; e += 8) {
        const int s0 = e_src[e], s1 = e_src[e + 4];
        uint4 u0 = *reinterpret_cast<const uint4*>(X + (size_t)s0 * 128 + off);
        uint4 u1 = *reinterpret_cast<const uint4*>(X + (size_t)s1 * 128 + off);
        const unsigned int* p0 = (const unsigned int*)&u0;
        const unsigned int* p1 = (const unsigned int*)&u1;
#pragma unroll
        for (int k = 0; k < 4; ++k) {
            acc[2 * k]     += ubits(p0[k] << 16) + ubits(p1[k] << 16);
            acc[2 * k + 1] += ubits(p0[k] & 0xFFFF0000u) + ubits(p1[k] & 0xFFFF0000u);
        }
    }
    if (e < end) {
        const int s = e_src[e];
        uint4 u = *reinterpret_cast<const uint4*>(X + (size_t)s * 128 + off);
        const unsigned int* p = (const unsigned int*)&u;
#pragma unroll
        for (int k = 0; k < 4; ++k) {
            acc[2 * k]     += ubits(p[k] << 16);
            acc[2 * k + 1] += ubits(p[k] & 0xFFFF0000u);
        }
    }

#pragma unroll
    for (int k = 0; k < 8; ++k) acc[k] += __shfl_xor(acc[k], 32);
#pragma unroll
    for (int k = 0; k < 8; ++k) acc[k] += __shfl_xor(acc[k], 16);

    if (qw == 0) {
        ushort4 o0, o1;
        o0.x = f2b(acc[0]); o0.y = f2b(acc[1]); o0.z = f2b(acc[2]); o0.w = f2b(acc[3]);
        o1.x = f2b(acc[4]); o1.y = f2b(acc[5]); o1.z = f2b(acc[6]); o1.w = f2b(acc[7]);
        unsigned short* p = agg + (size_t)node * 128 + off;
        *reinterpret_cast<ushort4*>(p) = o0;
        *reinterpret_cast<ushort4*>(p + 4) = o1;
    }
}

// ---------------------------------------------------------------------------
// Fused MLP v3 (round 9): weights live in VGPRs, loaded ONCE per block from
// fragment-order packs (coalesced, outside the MFMA chain — unlike round 7's
// per-K-step global loads). No weight LDS staging, no staging barriers.
// Barriers: A-ready, T-ready (+1 FUSE for Hf). Sequential-c stage 1 keeps
// live VGPRs ~190 (wb2[32]=128 + acc + misc); launch_bounds(256,2) caps 256.
// LDS: A[64][136]=17408 | T[64][264]=33792 (disjoint) | FUSE Hf[64][136].
// ---------------------------------------------------------------------------
template <bool FUSE>
__global__ __launch_bounds__(256, 2) void mlp_fused(
    const unsigned short* __restrict__ X, const unsigned short* __restrict__ Wp1,
    const float* __restrict__ b1, const unsigned short* __restrict__ Wp2,
    const float* __restrict__ b2, unsigned short* __restrict__ Y,
    const unsigned short* __restrict__ Wfct, const float* __restrict__ bfc,
    float* __restrict__ out, int M) {
    __shared__ __align__(16) char smem[FUSE ? 68608 : 51200];
    unsigned short* A  = (unsigned short*)smem;             // [64][136]
    unsigned short* T  = (unsigned short*)(smem + 17408);   // [64][264]
    unsigned short* Hf = (unsigned short*)(smem + 51200);   // [64][136] FUSE

    const int tid = threadIdx.x;
    const int m0 = blockIdx.x * 64;
    const int lane = tid & 63, w = tid >> 6;
    const int qm = lane & 15, quad = lane >> 4;

    // ---- stage-1 weight fragments -> VGPRs (16 coalesced 16B loads) ----
    short8 wb1[16];
#pragma unroll
    for (int v = 0; v < 16; ++v)
        wb1[v] = *reinterpret_cast<const short8*>(Wp1 + ((v * 256 + tid) << 3));

    // ---- load A (64 x 128 bf16) ----
#pragma unroll
    for (int j = 0; j < 4; ++j) {
        int i = j * 256 + tid;
        int r = i >> 4, c8 = (i & 15) << 3;
        uint4 v = {0, 0, 0, 0};
        if (m0 + r < M) v = *reinterpret_cast<const uint4*>(X + (size_t)(m0 + r) * 128 + c8);
        *reinterpret_cast<uint4*>(&A[r * 136 + c8]) = v;
    }
    __syncthreads();   // A ready

    // ---- stage 1: T = relu(A @ W1 + b1), sequential over c halves ----
#pragma unroll
    for (int c = 0; c < 2; ++c) {
        floatx4 acc1[4][2];
#pragma unroll
        for (int mt = 0; mt < 4; ++mt)
#pragma unroll
            for (int nt = 0; nt < 2; ++nt) acc1[mt][nt] = {0.f, 0.f, 0.f, 0.f};
#pragma unroll
        for (int ks = 0; ks < 4; ++ks) {
            const int kb = ks * 32 + quad * 8;
            short8 a[4];
#pragma unroll
            for (int mt = 0; mt < 4; ++mt)
                a[mt] = *reinterpret_cast<const short8*>(&A[(mt * 16 + qm) * 136 + kb]);
#pragma unroll
            for (int mt = 0; mt < 4; ++mt)
#pragma unroll
                for (int nt = 0; nt < 2; ++nt)
                    acc1[mt][nt] = __builtin_amdgcn_mfma_f32_16x16x32_bf16(
                        a[mt], wb1[c * 8 + ks * 2 + nt], acc1[mt][nt], 0, 0, 0);
        }
        // epilogue for this half: T cols c*128..+128 (A,T disjoint — no sync)
#pragma unroll
        for (int nt = 0; nt < 2; ++nt) {
            const int jcol = c * 128 + w * 32 + nt * 16 + qm;
            const float bj = b1[jcol];
#pragma unroll
            for (int mt = 0; mt < 4; ++mt)
#pragma unroll
                for (int r = 0; r < 4; ++r)
                    T[(mt * 16 + quad * 4 + r) * 264 + jcol] =
                        f2b(fmaxf(acc1[mt][nt][r] + bj, 0.f));
        }
    }

    // ---- stage-2 weight fragments -> VGPRs (32 coalesced 16B loads) ----
    short8 wb2[32];
#pragma unroll
    for (int v = 0; v < 32; ++v)
        wb2[v] = *reinterpret_cast<const short8*>(Wp2 + ((v * 256 + tid) << 3));
    __syncthreads();   // T ready

    // ---- stage 2: h = relu(T @ W2 + b2) ----
#pragma unroll
    for (int c2 = 0; c2 < 4; ++c2) {
        floatx4 acc2[2];
        acc2[0] = {0.f, 0.f, 0.f, 0.f};
        acc2[1] = {0.f, 0.f, 0.f, 0.f};
#pragma unroll
        for (int ks = 0; ks < 8; ++ks) {
            const int kb = ks * 32 + quad * 8;
            short8 t0 = *reinterpret_cast<const short8*>(&T[((w & 1) * 32 + qm) * 264 + kb]);
            short8 t1 = *reinterpret_cast<const short8*>(&T[((w & 1) * 32 + 16 + qm) * 264 + kb]);
            acc2[0] = __builtin_amdgcn_mfma_f32_16x16x32_bf16(t0, wb2[c2 * 8 + ks], acc2[0], 0, 0, 0);
            acc2[1] = __builtin_amdgcn_mfma_f32_16x16x32_bf16(t1, wb2[c2 * 8 + ks], acc2[1], 0, 0, 0);
        }

        const int ncol = c2 * 32 + (w >> 1) * 16 + qm;   // global h col
        const float bj = b2[ncol];
        if (!FUSE) {
#pragma unroll
            for (int mt2 = 0; mt2 < 2; ++mt2)
#pragma unroll
                for (int r = 0; r < 4; ++r) {
                    int row = m0 + (w & 1) * 32 + mt2 * 16 + quad * 4 + r;
                    if (row < M)
                        Y[(size_t)row * 128 + ncol] = f2b(fmaxf(acc2[mt2][r] + bj, 0.f));
                }
        } else {
#pragma unroll
            for (int mt2 = 0; mt2 < 2; ++mt2)
#pragma unroll
                for (int r = 0; r < 4; ++r)
                    Hf[((w & 1) * 32 + mt2 * 16 + quad * 4 + r) * 136 + ncol] =
                        f2b(fmaxf(acc2[mt2][r] + bj, 0.f));
        }
    }

    if (FUSE) {
        __syncthreads();   // Hf ready
        // ---- classifier: out = h @ Wfct^T + bfc, single pass over Hf ----
        floatx4 cacc[3];
#pragma unroll
        for (int nt = 0; nt < 3; ++nt) cacc[nt] = {0.f, 0.f, 0.f, 0.f};
#pragma unroll
        for (int c2 = 0; c2 < 4; ++c2) {
            short8 hf = *reinterpret_cast<const short8*>(
                &Hf[(w * 16 + qm) * 136 + c2 * 32 + quad * 8]);
#pragma unroll
            for (int nt = 0; nt < 3; ++nt) {
                short8 bf = *reinterpret_cast<const short8*>(
                    Wfct + (nt * 16 + qm) * 128 + c2 * 32 + quad * 8);
                cacc[nt] = __builtin_amdgcn_mfma_f32_16x16x32_bf16(hf, bf, cacc[nt], 0, 0, 0);
            }
        }
#pragma unroll
        for (int nt = 0; nt < 3; ++nt) {
            int col = nt * 16 + qm;
            if (col < 40) {
                const float bj = bfc[col];
#pragma unroll
                for (int r = 0; r < 4; ++r) {
                    int row = m0 + w * 16 + quad * 4 + r;
                    if (row < M) out[(size_t)row * 40 + col] = cacc[nt][r] + bj;
                }
            }
        }
    }
}

// ---------------------------------------------------------------------------
extern "C" void kernel_launch(void* const* d_in, const int* in_sizes, int n_in,
                              void* d_out, int out_size, void* d_ws, size_t ws_size,
                              hipStream_t stream) {
    const float* x   = (const float*)d_in[0];
    const int*   ei  = (const int*)d_in[1];
    const float* W11 = (const float*)d_in[2];
    const float* b11 = (const float*)d_in[3];
    const float* W12 = (const float*)d_in[4];
    const float* b12 = (const float*)d_in[5];
    const float* W21 = (const float*)d_in[6];
    const float* b21 = (const float*)d_in[7];
    const float* W22 = (const float*)d_in[8];
    const float* b22 = (const float*)d_in[9];
    const float* Wfc = (const float*)d_in[10];
    const float* bfc = (const float*)d_in[11];
    float* out = (float*)d_out;

    const int* srcv = ei;
    const int* dstv = ei + N_EDGES;

    unsigned short* agg  = (unsigned short*)d_ws;               // 50000*128 bf16
    unsigned short* h    = agg + (size_t)N_NODES * 128;
    unsigned short* xb   = h   + (size_t)N_NODES * 128;
    unsigned short* Wp11 = xb  + (size_t)N_NODES * 128;         // 32768
    unsigned short* Wp12 = Wp11 + 32768;                        // 65536 (2x dup)
    unsigned short* Wp21 = Wp12 + 65536;                        // 32768
    unsigned short* Wp22 = Wp21 + 32768;                        // 65536
    unsigned short* Wfct = Wp22 + 65536;                        // 48*128
    int* cnt     = (int*)(Wfct + 48 * 128);                     // 392*391 (pad 153664)
    int* sbase   = cnt + 153664;                                // 392*392
    int* row_ptr = sbase + 153664;                              // 392*129 (pad 50688)
    int* e_src   = row_ptr + 50688;                             // 392*2560
    int* bufc    = e_src + (size_t)NBUCK * CAPB;                // 392*2560

    // ---- K1a: per-(block,bucket) hist + x->bf16 ----
    hist_conv<<<NSB + 3125, 256, 0, stream>>>(dstv, x, cnt, xb);

    // ---- K1b: strip-base scan + fragment-order weight packing (cover) ----
    scan_conv<<<NBUCK + 792, 256, 0, stream>>>(
        cnt, sbase, W11, W12, W21, W22, Wfc,
        Wp11, Wp12, Wp21, Wp22, Wfct);

    // ---- K1c: compacted placement (plain stores into reserved runs) ----
    place_compact<<<NSB, 256, 0, stream>>>(srcv, dstv, sbase, bufc);

    // ---- K2: per-bucket finish: hist/scan/place from contiguous input ----
    finish_buckets<<<NBUCK, 256, 0, stream>>>(sbase, bufc, e_src, row_ptr);

    const int agg_blocks = N_NODES * 64 / 256;        // 12500, one wave per node
    const int mlp_blocks = (N_NODES + 63) / 64;       // 782

    // ---- layer 1 ----
    agg_bf16q<<<agg_blocks, 256, 0, stream>>>(xb, row_ptr, e_src, agg);
    mlp_fused<false><<<mlp_blocks, 256, 0, stream>>>(
        agg, Wp11, b11, Wp12, b12, h, nullptr, nullptr, nullptr, N_NODES);
    // ---- layer 2 + classifier ----
    agg_bf16q<<<agg_blocks, 256, 0, stream>>>(h, row_ptr, e_src, agg);
    mlp_fused<true><<<mlp_blocks, 256, 0, stream>>>(
        agg, Wp21, b21, Wp22, b22, nullptr, Wfct, bfc, out, N_NODES);
}

// Round 10
// 223.762 us; speedup vs baseline: 1.0913x; 1.0104x over previous
//
#include <hip/hip_runtime.h>

#define N_NODES 50000
#define N_EDGES 800000
#define NBUCK   392           // buckets of 128 nodes (dst >> 7)
#define EPB     2048          // edges per scatter block
#define NSB     391           // scatter blocks = ceil(800000/2048)
#define CAPB    2560          // per-bucket capacity (mean ~2041, +11 sigma)

typedef __attribute__((ext_vector_type(8))) short short8;
typedef __attribute__((ext_vector_type(4))) float floatx4;

__device__ __forceinline__ float ubits(unsigned int b) {
    union { unsigned int i; float f; } v;
    v.i = b;
    return v.f;
}
__device__ __forceinline__ unsigned short f2b(float f) {  // round-nearest-even
    union { float f; unsigned int i; } v;
    v.f = f;
    unsigned int r = v.i + 0x7FFFu + ((v.i >> 16) & 1u);
    return (unsigned short)(r >> 16);
}

// ---------------------------------------------------------------------------
// Fragment-order weight packs (round 9, kept). MLP holds weights in VGPRs;
// pack layout Wp[(v*256 + tid)*8 + j] makes the per-block register load
// fully coalesced (one 16B load per (v, tid)).
// ---------------------------------------------------------------------------
__device__ __forceinline__ void pack_s1(const float* __restrict__ W,
                                        unsigned short* __restrict__ Wp,
                                        int blk, int tid) {
    int p = blk * 256 + tid;                 // [0, 32768)
    int j = p & 7, t2 = (p >> 3) & 255, v = p >> 11;
    int w = t2 >> 6, lane = t2 & 63, quad = lane >> 4, qm = lane & 15;
    int c = v >> 3, ks = (v >> 1) & 3, nt = v & 1;
    int k = ks * 32 + quad * 8 + j;
    int n = c * 128 + w * 32 + nt * 16 + qm;
    Wp[p] = f2b(W[k * 256 + n]);
}
__device__ __forceinline__ void pack_s2(const float* __restrict__ W,
                                        unsigned short* __restrict__ Wp,
                                        int blk, int tid) {
    int p = blk * 256 + tid;                 // [0, 65536)
    int j = p & 7, t2 = (p >> 3) & 255, v2 = p >> 11;
    int w = t2 >> 6, lane = t2 & 63, quad = lane >> 4, qm = lane & 15;
    int c2 = v2 >> 3, ks = v2 & 7;
    int k = ks * 32 + quad * 8 + j;
    int n = c2 * 32 + (w >> 1) * 16 + qm;
    Wp[p] = f2b(W[k * 128 + n]);
}

// ---------------------------------------------------------------------------
// K1 (round 10): single-pass scatter — hist + global run-reservation + place.
// Replaces hist_conv/scan_conv/place_compact: edges are read ONCE into
// registers; per-(block,bucket) runs reserved via one atomicAdd(&bcount[b],c)
// each (153k atomics on 392 counters — cheap, unlike round 4's 800k
// single-cursor thrash). bufc entry: src | dloc<<16.
// [0,391): scatter.  [391,3516): x -> bf16 cover.
// bcount must be zeroed before launch (hipMemsetAsync).
// ---------------------------------------------------------------------------
__global__ __launch_bounds__(256) void scatter_all(
    const int* __restrict__ srcv, const int* __restrict__ dstv,
    const float* __restrict__ x,
    int* __restrict__ bcount, int* __restrict__ bufc,
    unsigned short* __restrict__ xb) {
    const int bid = blockIdx.x;
    const int tid = threadIdx.x;
    if (bid < NSB) {
        __shared__ int hist[NBUCK];
        __shared__ int base[NBUCK];
        const int e0 = bid * EPB;
        int d[8], s[8];
#pragma unroll
        for (int j = 0; j < 8; ++j) {
            int e = e0 + j * 256 + tid;
            if (e < N_EDGES) { d[j] = dstv[e]; s[j] = srcv[e]; }
            else d[j] = -1;
        }
        for (int i = tid; i < NBUCK; i += 256) hist[i] = 0;
        __syncthreads();
#pragma unroll
        for (int j = 0; j < 8; ++j)
            if (d[j] >= 0) atomicAdd(&hist[d[j] >> 7], 1);
        __syncthreads();
        for (int i = tid; i < NBUCK; i += 256) {
            int c = hist[i];
            base[i] = c ? atomicAdd(&bcount[i], c) : 0;
            hist[i] = 0;
        }
        __syncthreads();
#pragma unroll
        for (int j = 0; j < 8; ++j) {
            if (d[j] >= 0) {
                int b = d[j] >> 7;
                int r = atomicAdd(&hist[b], 1);
                bufc[b * CAPB + base[b] + r] = s[j] | ((d[j] & 127) << 16);
            }
        }
    } else {
        int i = (bid - NSB) * 256 + tid;             // 800000 groups of 8
        const float4 a = *reinterpret_cast<const float4*>(x + (size_t)i * 8);
        const float4 b = *reinterpret_cast<const float4*>(x + (size_t)i * 8 + 4);
        ushort4 u0, u1;
        u0.x = f2b(a.x); u0.y = f2b(a.y); u0.z = f2b(a.z); u0.w = f2b(a.w);
        u1.x = f2b(b.x); u1.y = f2b(b.y); u1.z = f2b(b.z); u1.w = f2b(b.w);
        *reinterpret_cast<ushort4*>(xb + (size_t)i * 8) = u0;
        *reinterpret_cast<ushort4*>(xb + (size_t)i * 8 + 4) = u1;
    }
}

// ---------------------------------------------------------------------------
// K2 (round 10): per-bucket finish + weight packing cover.
// [0,392): node hist from compacted input, 128-wide scan -> row_ptr
// (129-stride), place into e_src.  S_b comes from bcount.
// [392,520): W11.  [520,776): W12.  [776,904): W21.  [904,1160): W22.
// [1160,1184): Wfct.
// ---------------------------------------------------------------------------
__global__ __launch_bounds__(256) void finish_conv(
    const int* __restrict__ bcount, const int* __restrict__ bufc,
    int* __restrict__ e_src, int* __restrict__ row_ptr,
    const float* __restrict__ W11, const float* __restrict__ W12,
    const float* __restrict__ W21, const float* __restrict__ W22,
    const float* __restrict__ Wfc,
    unsigned short* __restrict__ Wp11, unsigned short* __restrict__ Wp12,
    unsigned short* __restrict__ Wp21, unsigned short* __restrict__ Wp22,
    unsigned short* __restrict__ Wfct) {
    const int bid = blockIdx.x;
    const int tid = threadIdx.x;
    if (bid < NBUCK) {
        __shared__ int nc[128];
        __shared__ int ps[128];
        const int b = bid;
        const int S = bcount[b];
        const int gb = b * CAPB;
        if (tid < 128) nc[tid] = 0;
        __syncthreads();
        for (int t = tid; t < S; t += 256)
            atomicAdd(&nc[(bufc[gb + t] >> 16) & 127], 1);
        __syncthreads();
        if (tid < 128) ps[tid] = nc[tid];
        __syncthreads();
        for (int off = 1; off < 128; off <<= 1) {
            int u = (tid >= off && tid < 128) ? ps[tid - off] : 0;
            __syncthreads();
            if (tid < 128) ps[tid] += u;
            __syncthreads();
        }
        if (tid < 128) {
            const int excl = ps[tid] - nc[tid];
            row_ptr[b * 129 + tid] = gb + excl;
            nc[tid] = gb + excl;                 // absolute cursor
        }
        if (tid == 0) row_ptr[b * 129 + 128] = gb + S;
        __syncthreads();
        for (int t = tid; t < S; t += 256) {
            int p = bufc[gb + t];
            int pos = atomicAdd(&nc[(p >> 16) & 127], 1);
            e_src[pos] = p & 0xFFFF;
        }
    } else if (bid < NBUCK + 128) {
        pack_s1(W11, Wp11, bid - NBUCK, tid);
    } else if (bid < NBUCK + 384) {
        pack_s2(W12, Wp12, bid - NBUCK - 128, tid);
    } else if (bid < NBUCK + 512) {
        pack_s1(W21, Wp21, bid - NBUCK - 384, tid);
    } else if (bid < NBUCK + 768) {
        pack_s2(W22, Wp22, bid - NBUCK - 512, tid);
    } else {
        int idx = (bid - NBUCK - 768) * 256 + tid;   // 6144 = 48*128
        int n = idx >> 7, k = idx & 127;
        Wfct[idx] = (n < 40) ? f2b(Wfc[k * 40 + n]) : (unsigned short)0;
    }
}

// ---------------------------------------------------------------------------
// aggregate: agg[i] = x[i] + sum_{e in row i} x[e_src[e]]  — one wave/node.
// Quarter-wave split (16 lanes x ushort8 = 256B row), 4 edge streams/wave,
// unroll x4 -> 16 row-loads in flight. row_ptr is 129-strided per bucket.
// ---------------------------------------------------------------------------
__global__ __launch_bounds__(256) void agg_bf16q(const unsigned short* __restrict__ X,
                                                 const int* __restrict__ row_ptr,
                                                 const int* __restrict__ e_src,
                                                 unsigned short* __restrict__ agg) {
    const int node = (blockIdx.x * 256 + threadIdx.x) >> 6;
    const int lane = threadIdx.x & 63;
    const int qw = lane >> 4, ql = lane & 15;
    const size_t off = (size_t)ql * 8;

    const int rp = node + (node >> 7);
    const int beg = row_ptr[rp], end = row_ptr[rp + 1];
    float acc[8];
#pragma unroll
    for (int k = 0; k < 8; ++k) acc[k] = 0.f;

    if (qw == 0) {
        uint4 u = *reinterpret_cast<const uint4*>(X + (size_t)node * 128 + off);
        const unsigned int* up = (const unsigned int*)&u;
#pragma unroll
        for (int k = 0; k < 4; ++k) {
            acc[2 * k]     += ubits(up[k] << 16);
            acc[2 * k + 1] += ubits(up[k] & 0xFFFF0000u);
        }
    }

    int e = beg + qw;
    for (; e + 12 < end; e += 16) {
        const int s0 = e_src[e], s1 = e_src[e + 4], s2 = e_src[e + 8], s3 = e_src[e + 12];
        uint4 u0 = *reinterpret_cast<const uint4*>(X + (size_t)s0 * 128 + off);
        uint4 u1 = *reinterpret_cast<const uint4*>(X + (size_t)s1 * 128 + off);
        uint4 u2 = *reinterpret_cast<const uint4*>(X + (size_t)s2 * 128 + off);
        uint4 u3 = *reinterpret_cast<const uint4*>(X + (size_t)s3 * 128 + off);
        const unsigned int* p0 = (const unsigned int*)&u0;
        const unsigned int* p1 = (const unsigned int*)&u1;
        const unsigned int* p2 = (const unsigned int*)&u2;
        const unsigned int* p3 = (const unsigned int*)&u3;
#pragma unroll
        for (int k = 0; k < 4; ++k) {
            acc[2 * k]     += ubits(p0[k] << 16) + ubits(p1[k] << 16)
                            + ubits(p2[k] << 16) + ubits(p3[k] << 16);
            acc[2 * k + 1] += ubits(p0[k] & 0xFFFF0000u) + ubits(p1[k] & 0xFFFF0000u)
                            + ubits(p2[k] & 0xFFFF0000u) + ubits(p3[k] & 0xFFFF0000u);
        }
    }
    for (; e + 4 < end; e += 8) {
        const int s0 = e_src[e], s1 = e_src[e + 4];
        uint4 u0 = *reinterpret_cast<const uint4*>(X + (size_t)s0 * 128 + off);
        uint4 u1 = *reinterpret_cast<const uint4*>(X + (size_t)s1 * 128 + off);
        const unsigned int* p0 = (const unsigned int*)&u0;
        const unsigned int* p1 = (const unsigned int*)&u1;
#pragma unroll
        for (int k = 0; k < 4; ++k) {
            acc[2 * k]     += ubits(p0[k] << 16) + ubits(p1[k] << 16);
            acc[2 * k + 1] += ubits(p0[k] & 0xFFFF0000u) + ubits(p1[k] & 0xFFFF0000u);
        }
    }
    if (e < end) {
        const int s = e_src[e];
        uint4 u = *reinterpret_cast<const uint4*>(X + (size_t)s * 128 + off);
        const unsigned int* p = (const unsigned int*)&u;
#pragma unroll
        for (int k = 0; k < 4; ++k) {
            acc[2 * k]     += ubits(p[k] << 16);
            acc[2 * k + 1] += ubits(p[k] & 0xFFFF0000u);
        }
    }

#pragma unroll
    for (int k = 0; k < 8; ++k) acc[k] += __shfl_xor(acc[k], 32);
#pragma unroll
    for (int k = 0; k < 8; ++k) acc[k] += __shfl_xor(acc[k], 16);

    if (qw == 0) {
        ushort4 o0, o1;
        o0.x = f2b(acc[0]); o0.y = f2b(acc[1]); o0.z = f2b(acc[2]); o0.w = f2b(acc[3]);
        o1.x = f2b(acc[4]); o1.y = f2b(acc[5]); o1.z = f2b(acc[6]); o1.w = f2b(acc[7]);
        unsigned short* p = agg + (size_t)node * 128 + off;
        *reinterpret_cast<ushort4*>(p) = o0;
        *reinterpret_cast<ushort4*>(p + 4) = o1;
    }
}

// ---------------------------------------------------------------------------
// Fused MLP v3 (round 9, kept): weights in VGPRs, loaded once per block from
// fragment-order packs. Barriers: A-ready, T-ready (+1 FUSE).
// LDS: A[64][136]=17408 | T[64][264]=33792 (disjoint) | FUSE Hf[64][136].
// ---------------------------------------------------------------------------
template <bool FUSE>
__global__ __launch_bounds__(256, 2) void mlp_fused(
    const unsigned short* __restrict__ X, const unsigned short* __restrict__ Wp1,
    const float* __restrict__ b1, const unsigned short* __restrict__ Wp2,
    const float* __restrict__ b2, unsigned short* __restrict__ Y,
    const unsigned short* __restrict__ Wfct, const float* __restrict__ bfc,
    float* __restrict__ out, int M) {
    __shared__ __align__(16) char smem[FUSE ? 68608 : 51200];
    unsigned short* A  = (unsigned short*)smem;             // [64][136]
    unsigned short* T  = (unsigned short*)(smem + 17408);   // [64][264]
    unsigned short* Hf = (unsigned short*)(smem + 51200);   // [64][136] FUSE

    const int tid = threadIdx.x;
    const int m0 = blockIdx.x * 64;
    const int lane = tid & 63, w = tid >> 6;
    const int qm = lane & 15, quad = lane >> 4;

    // ---- stage-1 weight fragments -> VGPRs (16 coalesced 16B loads) ----
    short8 wb1[16];
#pragma unroll
    for (int v = 0; v < 16; ++v)
        wb1[v] = *reinterpret_cast<const short8*>(Wp1 + ((v * 256 + tid) << 3));

    // ---- load A (64 x 128 bf16) ----
#pragma unroll
    for (int j = 0; j < 4; ++j) {
        int i = j * 256 + tid;
        int r = i >> 4, c8 = (i & 15) << 3;
        uint4 v = {0, 0, 0, 0};
        if (m0 + r < M) v = *reinterpret_cast<const uint4*>(X + (size_t)(m0 + r) * 128 + c8);
        *reinterpret_cast<uint4*>(&A[r * 136 + c8]) = v;
    }
    __syncthreads();   // A ready

    // ---- stage 1: T = relu(A @ W1 + b1), sequential over c halves ----
#pragma unroll
    for (int c = 0; c < 2; ++c) {
        floatx4 acc1[4][2];
#pragma unroll
        for (int mt = 0; mt < 4; ++mt)
#pragma unroll
            for (int nt = 0; nt < 2; ++nt) acc1[mt][nt] = {0.f, 0.f, 0.f, 0.f};
#pragma unroll
        for (int ks = 0; ks < 4; ++ks) {
            const int kb = ks * 32 + quad * 8;
            short8 a[4];
#pragma unroll
            for (int mt = 0; mt < 4; ++mt)
                a[mt] = *reinterpret_cast<const short8*>(&A[(mt * 16 + qm) * 136 + kb]);
#pragma unroll
            for (int mt = 0; mt < 4; ++mt)
#pragma unroll
                for (int nt = 0; nt < 2; ++nt)
                    acc1[mt][nt] = __builtin_amdgcn_mfma_f32_16x16x32_bf16(
                        a[mt], wb1[c * 8 + ks * 2 + nt], acc1[mt][nt], 0, 0, 0);
        }
        // epilogue for this half: T cols c*128..+128 (A,T disjoint — no sync)
#pragma unroll
        for (int nt = 0; nt < 2; ++nt) {
            const int jcol = c * 128 + w * 32 + nt * 16 + qm;
            const float bj = b1[jcol];
#pragma unroll
            for (int mt = 0; mt < 4; ++mt)
#pragma unroll
                for (int r = 0; r < 4; ++r)
                    T[(mt * 16 + quad * 4 + r) * 264 + jcol] =
                        f2b(fmaxf(acc1[mt][nt][r] + bj, 0.f));
        }
    }

    // ---- stage-2 weight fragments -> VGPRs (32 coalesced 16B loads) ----
    short8 wb2[32];
#pragma unroll
    for (int v = 0; v < 32; ++v)
        wb2[v] = *reinterpret_cast<const short8*>(Wp2 + ((v * 256 + tid) << 3));
    __syncthreads();   // T ready

    // ---- stage 2: h = relu(T @ W2 + b2) ----
#pragma unroll
    for (int c2 = 0; c2 < 4; ++c2) {
        floatx4 acc2[2];
        acc2[0] = {0.f, 0.f, 0.f, 0.f};
        acc2[1] = {0.f, 0.f, 0.f, 0.f};
#pragma unroll
        for (int ks = 0; ks < 8; ++ks) {
            const int kb = ks * 32 + quad * 8;
            short8 t0 = *reinterpret_cast<const short8*>(&T[((w & 1) * 32 + qm) * 264 + kb]);
            short8 t1 = *reinterpret_cast<const short8*>(&T[((w & 1) * 32 + 16 + qm) * 264 + kb]);
            acc2[0] = __builtin_amdgcn_mfma_f32_16x16x32_bf16(t0, wb2[c2 * 8 + ks], acc2[0], 0, 0, 0);
            acc2[1] = __builtin_amdgcn_mfma_f32_16x16x32_bf16(t1, wb2[c2 * 8 + ks], acc2[1], 0, 0, 0);
        }

        const int ncol = c2 * 32 + (w >> 1) * 16 + qm;   // global h col
        const float bj = b2[ncol];
        if (!FUSE) {
#pragma unroll
            for (int mt2 = 0; mt2 < 2; ++mt2)
#pragma unroll
                for (int r = 0; r < 4; ++r) {
                    int row = m0 + (w & 1) * 32 + mt2 * 16 + quad * 4 + r;
                    if (row < M)
                        Y[(size_t)row * 128 + ncol] = f2b(fmaxf(acc2[mt2][r] + bj, 0.f));
                }
        } else {
#pragma unroll
            for (int mt2 = 0; mt2 < 2; ++mt2)
#pragma unroll
                for (int r = 0; r < 4; ++r)
                    Hf[((w & 1) * 32 + mt2 * 16 + quad * 4 + r) * 136 + ncol] =
                        f2b(fmaxf(acc2[mt2][r] + bj, 0.f));
        }
    }

    if (FUSE) {
        __syncthreads();   // Hf ready
        // ---- classifier: out = h @ Wfct^T + bfc, single pass over Hf ----
        floatx4 cacc[3];
#pragma unroll
        for (int nt = 0; nt < 3; ++nt) cacc[nt] = {0.f, 0.f, 0.f, 0.f};
#pragma unroll
        for (int c2 = 0; c2 < 4; ++c2) {
            short8 hf = *reinterpret_cast<const short8*>(
                &Hf[(w * 16 + qm) * 136 + c2 * 32 + quad * 8]);
#pragma unroll
            for (int nt = 0; nt < 3; ++nt) {
                short8 bf = *reinterpret_cast<const short8*>(
                    Wfct + (nt * 16 + qm) * 128 + c2 * 32 + quad * 8);
                cacc[nt] = __builtin_amdgcn_mfma_f32_16x16x32_bf16(hf, bf, cacc[nt], 0, 0, 0);
            }
        }
#pragma unroll
        for (int nt = 0; nt < 3; ++nt) {
            int col = nt * 16 + qm;
            if (col < 40) {
                const float bj = bfc[col];
#pragma unroll
                for (int r = 0; r < 4; ++r) {
                    int row = m0 + w * 16 + quad * 4 + r;
                    if (row < M) out[(size_t)row * 40 + col] = cacc[nt][r] + bj;
                }
            }
        }
    }
}

// ---------------------------------------------------------------------------
extern "C" void kernel_launch(void* const* d_in, const int* in_sizes, int n_in,
                              void* d_out, int out_size, void* d_ws, size_t ws_size,
                              hipStream_t stream) {
    const float* x   = (const float*)d_in[0];
    const int*   ei  = (const int*)d_in[1];
    const float* W11 = (const float*)d_in[2];
    const float* b11 = (const float*)d_in[3];
    const float* W12 = (const float*)d_in[4];
    const float* b12 = (const float*)d_in[5];
    const float* W21 = (const float*)d_in[6];
    const float* b21 = (const float*)d_in[7];
    const float* W22 = (const float*)d_in[8];
    const float* b22 = (const float*)d_in[9];
    const float* Wfc = (const float*)d_in[10];
    const float* bfc = (const float*)d_in[11];
    float* out = (float*)d_out;

    const int* srcv = ei;
    const int* dstv = ei + N_EDGES;

    unsigned short* agg  = (unsigned short*)d_ws;               // 50000*128 bf16
    unsigned short* h    = agg + (size_t)N_NODES * 128;
    unsigned short* xb   = h   + (size_t)N_NODES * 128;
    unsigned short* Wp11 = xb  + (size_t)N_NODES * 128;         // 32768
    unsigned short* Wp12 = Wp11 + 32768;                        // 65536 (2x dup)
    unsigned short* Wp21 = Wp12 + 65536;                        // 32768
    unsigned short* Wp22 = Wp21 + 32768;                        // 65536
    unsigned short* Wfct = Wp22 + 65536;                        // 48*128
    int* bcount  = (int*)(Wfct + 48 * 128);                     // 392 (pad 512)
    int* row_ptr = bcount + 512;                                // 392*129 (pad 50688)
    int* e_src   = row_ptr + 50688;                             // 392*2560
    int* bufc    = e_src + (size_t)NBUCK * CAPB;                // 392*2560

    // ---- zero reservation counters (tiny, capture-safe) ----
    hipMemsetAsync(bcount, 0, NBUCK * sizeof(int), stream);

    // ---- K1: single-pass scatter (hist + reserve + place) + x->bf16 ----
    scatter_all<<<NSB + 3125, 256, 0, stream>>>(srcv, dstv, x, bcount, bufc, xb);

    // ---- K2: per-bucket finish + weight packing cover ----
    finish_conv<<<NBUCK + 792, 256, 0, stream>>>(
        bcount, bufc, e_src, row_ptr,
        W11, W12, W21, W22, Wfc,
        Wp11, Wp12, Wp21, Wp22, Wfct);

    const int agg_blocks = N_NODES * 64 / 256;        // 12500, one wave per node
    const int mlp_blocks = (N_NODES + 63) / 64;       // 782

    // ---- layer 1 ----
    agg_bf16q<<<agg_blocks, 256, 0, stream>>>(xb, row_ptr, e_src, agg);
    mlp_fused<false><<<mlp_blocks, 256, 0, stream>>>(
        agg, Wp11, b11, Wp12, b12, h, nullptr, nullptr, nullptr, N_NODES);
    // ---- layer 2 + classifier ----
    agg_bf16q<<<agg_blocks, 256, 0, stream>>>(h, row_ptr, e_src, agg);
    mlp_fused<true><<<mlp_blocks, 256, 0, stream>>>(
        agg, Wp21, b21, Wp22, b22, nullptr, Wfct, bfc, out, N_NODES);
}

// Round 11
// 222.801 us; speedup vs baseline: 1.0960x; 1.0043x over previous
//
#include <hip/hip_runtime.h>

#define N_NODES 50000
#define N_EDGES 800000
#define NBUCK   392           // buckets of 128 nodes (dst >> 7)
#define EPB     2048          // edges per scatter block
#define NSB     391           // scatter blocks = ceil(800000/2048)
#define CAPB    2560          // per-bucket capacity (mean ~2041, +11 sigma)

typedef __attribute__((ext_vector_type(8))) short short8;
typedef __attribute__((ext_vector_type(4))) float floatx4;

__device__ __forceinline__ float ubits(unsigned int b) {
    union { unsigned int i; float f; } v;
    v.i = b;
    return v.f;
}
__device__ __forceinline__ unsigned short f2b(float f) {  // round-nearest-even
    union { float f; unsigned int i; } v;
    v.f = f;
    unsigned int r = v.i + 0x7FFFu + ((v.i >> 16) & 1u);
    return (unsigned short)(r >> 16);
}

// ---------------------------------------------------------------------------
// Fragment-order weight packs (round 9, kept). MLP holds weights in VGPRs;
// pack layout Wp[(v*256 + tid)*8 + j] makes the per-block register load
// fully coalesced (one 16B load per (v, tid)).
// ---------------------------------------------------------------------------
__device__ __forceinline__ void pack_s1(const float* __restrict__ W,
                                        unsigned short* __restrict__ Wp,
                                        int blk, int tid) {
    int p = blk * 256 + tid;                 // [0, 32768)
    int j = p & 7, t2 = (p >> 3) & 255, v = p >> 11;
    int w = t2 >> 6, lane = t2 & 63, quad = lane >> 4, qm = lane & 15;
    int c = v >> 3, ks = (v >> 1) & 3, nt = v & 1;
    int k = ks * 32 + quad * 8 + j;
    int n = c * 128 + w * 32 + nt * 16 + qm;
    Wp[p] = f2b(W[k * 256 + n]);
}
__device__ __forceinline__ void pack_s2(const float* __restrict__ W,
                                        unsigned short* __restrict__ Wp,
                                        int blk, int tid) {
    int p = blk * 256 + tid;                 // [0, 65536)
    int j = p & 7, t2 = (p >> 3) & 255, v2 = p >> 11;
    int w = t2 >> 6, lane = t2 & 63, quad = lane >> 4, qm = lane & 15;
    int c2 = v2 >> 3, ks = v2 & 7;
    int k = ks * 32 + quad * 8 + j;
    int n = c2 * 32 + (w >> 1) * 16 + qm;
    Wp[p] = f2b(W[k * 128 + n]);
}

// ---------------------------------------------------------------------------
// K1 (round 11): single-pass scatter with VECTORIZED edge loads.
// Thread t_e = bid*256+tid owns 8 contiguous edges [t_e*8, t_e*8+8)
// -> 2 uint4 loads for dst + 2 for src (32B/lane, coalesced), replacing 16
// scalar loads. Mapping change is harmless: hist/reserve/place are
// per-edge-order-independent. 100000 owning threads (block 390: tid<160).
// [0,391): scatter.  [391,3516): x -> bf16 cover.
// bcount must be zeroed before launch (hipMemsetAsync).
// ---------------------------------------------------------------------------
__global__ __launch_bounds__(256) void scatter_all(
    const int* __restrict__ srcv, const int* __restrict__ dstv,
    const float* __restrict__ x,
    int* __restrict__ bcount, int* __restrict__ bufc,
    unsigned short* __restrict__ xb) {
    const int bid = blockIdx.x;
    const int tid = threadIdx.x;
    if (bid < NSB) {
        __shared__ int hist[NBUCK];
        __shared__ int base[NBUCK];
        const int te = bid * 256 + tid;          // [0, 100096); valid < 100000
        const bool ok = te < (N_EDGES / 8);
        int d[8], s[8];
        if (ok) {
            const uint4* dp = reinterpret_cast<const uint4*>(dstv + (size_t)te * 8);
            const uint4* sp = reinterpret_cast<const uint4*>(srcv + (size_t)te * 8);
            uint4 d0 = dp[0], d1 = dp[1], s0 = sp[0], s1 = sp[1];
            d[0] = d0.x; d[1] = d0.y; d[2] = d0.z; d[3] = d0.w;
            d[4] = d1.x; d[5] = d1.y; d[6] = d1.z; d[7] = d1.w;
            s[0] = s0.x; s[1] = s0.y; s[2] = s0.z; s[3] = s0.w;
            s[4] = s1.x; s[5] = s1.y; s[6] = s1.z; s[7] = s1.w;
        }
        for (int i = tid; i < NBUCK; i += 256) hist[i] = 0;
        __syncthreads();
        if (ok) {
#pragma unroll
            for (int j = 0; j < 8; ++j) atomicAdd(&hist[d[j] >> 7], 1);
        }
        __syncthreads();
        for (int i = tid; i < NBUCK; i += 256) {
            int c = hist[i];
            base[i] = c ? atomicAdd(&bcount[i], c) : 0;
            hist[i] = 0;
        }
        __syncthreads();
        if (ok) {
#pragma unroll
            for (int j = 0; j < 8; ++j) {
                int b = d[j] >> 7;
                int r = atomicAdd(&hist[b], 1);
                bufc[b * CAPB + base[b] + r] = s[j] | ((d[j] & 127) << 16);
            }
        }
    } else {
        int i = (bid - NSB) * 256 + tid;             // 800000 groups of 8
        const float4 a = *reinterpret_cast<const float4*>(x + (size_t)i * 8);
        const float4 b = *reinterpret_cast<const float4*>(x + (size_t)i * 8 + 4);
        ushort4 u0, u1;
        u0.x = f2b(a.x); u0.y = f2b(a.y); u0.z = f2b(a.z); u0.w = f2b(a.w);
        u1.x = f2b(b.x); u1.y = f2b(b.y); u1.z = f2b(b.z); u1.w = f2b(b.w);
        *reinterpret_cast<ushort4*>(xb + (size_t)i * 8) = u0;
        *reinterpret_cast<ushort4*>(xb + (size_t)i * 8 + 4) = u1;
    }
}

// ---------------------------------------------------------------------------
// K2 (round 11): per-bucket finish with VECTORIZED bufc reads (uint4 = 4
// edges/load in both hist and place passes; CAPB%4==0 so gb is 16B-aligned).
// [0,392): finish.  [392,520): W11.  [520,776): W12.  [776,904): W21.
// [904,1160): W22.  [1160,1184): Wfct.
// ---------------------------------------------------------------------------
__global__ __launch_bounds__(256) void finish_conv(
    const int* __restrict__ bcount, const int* __restrict__ bufc,
    int* __restrict__ e_src, int* __restrict__ row_ptr,
    const float* __restrict__ W11, const float* __restrict__ W12,
    const float* __restrict__ W21, const float* __restrict__ W22,
    const float* __restrict__ Wfc,
    unsigned short* __restrict__ Wp11, unsigned short* __restrict__ Wp12,
    unsigned short* __restrict__ Wp21, unsigned short* __restrict__ Wp22,
    unsigned short* __restrict__ Wfct) {
    const int bid = blockIdx.x;
    const int tid = threadIdx.x;
    if (bid < NBUCK) {
        __shared__ int nc[128];
        __shared__ int ps[128];
        const int b = bid;
        const int S = bcount[b];
        const int gb = b * CAPB;
        const uint4* b4 = reinterpret_cast<const uint4*>(bufc + gb);
        const int nv = S >> 2;
        if (tid < 128) nc[tid] = 0;
        __syncthreads();
        for (int i = tid; i < nv; i += 256) {
            uint4 v = b4[i];
            atomicAdd(&nc[(v.x >> 16) & 127], 1);
            atomicAdd(&nc[(v.y >> 16) & 127], 1);
            atomicAdd(&nc[(v.z >> 16) & 127], 1);
            atomicAdd(&nc[(v.w >> 16) & 127], 1);
        }
        for (int t = (nv << 2) + tid; t < S; t += 256)
            atomicAdd(&nc[(bufc[gb + t] >> 16) & 127], 1);
        __syncthreads();
        if (tid < 128) ps[tid] = nc[tid];
        __syncthreads();
        for (int off = 1; off < 128; off <<= 1) {
            int u = (tid >= off && tid < 128) ? ps[tid - off] : 0;
            __syncthreads();
            if (tid < 128) ps[tid] += u;
            __syncthreads();
        }
        if (tid < 128) {
            const int excl = ps[tid] - nc[tid];
            row_ptr[b * 129 + tid] = gb + excl;
            nc[tid] = gb + excl;                 // absolute cursor
        }
        if (tid == 0) row_ptr[b * 129 + 128] = gb + S;
        __syncthreads();
        for (int i = tid; i < nv; i += 256) {
            uint4 v = b4[i];
            int p;
            p = atomicAdd(&nc[(v.x >> 16) & 127], 1); e_src[p] = v.x & 0xFFFF;
            p = atomicAdd(&nc[(v.y >> 16) & 127], 1); e_src[p] = v.y & 0xFFFF;
            p = atomicAdd(&nc[(v.z >> 16) & 127], 1); e_src[p] = v.z & 0xFFFF;
            p = atomicAdd(&nc[(v.w >> 16) & 127], 1); e_src[p] = v.w & 0xFFFF;
        }
        for (int t = (nv << 2) + tid; t < S; t += 256) {
            int pv = bufc[gb + t];
            int pos = atomicAdd(&nc[(pv >> 16) & 127], 1);
            e_src[pos] = pv & 0xFFFF;
        }
    } else if (bid < NBUCK + 128) {
        pack_s1(W11, Wp11, bid - NBUCK, tid);
    } else if (bid < NBUCK + 384) {
        pack_s2(W12, Wp12, bid - NBUCK - 128, tid);
    } else if (bid < NBUCK + 512) {
        pack_s1(W21, Wp21, bid - NBUCK - 384, tid);
    } else if (bid < NBUCK + 768) {
        pack_s2(W22, Wp22, bid - NBUCK - 512, tid);
    } else {
        int idx = (bid - NBUCK - 768) * 256 + tid;   // 6144 = 48*128
        int n = idx >> 7, k = idx & 127;
        Wfct[idx] = (n < 40) ? f2b(Wfc[k * 40 + n]) : (unsigned short)0;
    }
}

// ---------------------------------------------------------------------------
// aggregate: agg[i] = x[i] + sum_{e in row i} x[e_src[e]]  — one wave/node.
// Quarter-wave split (16 lanes x ushort8 = 256B row), 4 edge streams/wave,
// unroll x4 -> 16 row-loads in flight. row_ptr is 129-strided per bucket.
// ---------------------------------------------------------------------------
__global__ __launch_bounds__(256) void agg_bf16q(const unsigned short* __restrict__ X,
                                                 const int* __restrict__ row_ptr,
                                                 const int* __restrict__ e_src,
                                                 unsigned short* __restrict__ agg) {
    const int node = (blockIdx.x * 256 + threadIdx.x) >> 6;
    const int lane = threadIdx.x & 63;
    const int qw = lane >> 4, ql = lane & 15;
    const size_t off = (size_t)ql * 8;

    const int rp = node + (node >> 7);
    const int beg = row_ptr[rp], end = row_ptr[rp + 1];
    float acc[8];
#pragma unroll
    for (int k = 0; k < 8; ++k) acc[k] = 0.f;

    if (qw == 0) {
        uint4 u = *reinterpret_cast<const uint4*>(X + (size_t)node * 128 + off);
        const unsigned int* up = (const unsigned int*)&u;
#pragma unroll
        for (int k = 0; k < 4; ++k) {
            acc[2 * k]     += ubits(up[k] << 16);
            acc[2 * k + 1] += ubits(up[k] & 0xFFFF0000u);
        }
    }

    int e = beg + qw;
    for (; e + 12 < end; e += 16) {
        const int s0 = e_src[e], s1 = e_src[e + 4], s2 = e_src[e + 8], s3 = e_src[e + 12];
        uint4 u0 = *reinterpret_cast<const uint4*>(X + (size_t)s0 * 128 + off);
        uint4 u1 = *reinterpret_cast<const uint4*>(X + (size_t)s1 * 128 + off);
        uint4 u2 = *reinterpret_cast<const uint4*>(X + (size_t)s2 * 128 + off);
        uint4 u3 = *reinterpret_cast<const uint4*>(X + (size_t)s3 * 128 + off);
        const unsigned int* p0 = (const unsigned int*)&u0;
        const unsigned int* p1 = (const unsigned int*)&u1;
        const unsigned int* p2 = (const unsigned int*)&u2;
        const unsigned int* p3 = (const unsigned int*)&u3;
#pragma unroll
        for (int k = 0; k < 4; ++k) {
            acc[2 * k]     += ubits(p0[k] << 16) + ubits(p1[k] << 16)
                            + ubits(p2[k] << 16) + ubits(p3[k] << 16);
            acc[2 * k + 1] += ubits(p0[k] & 0xFFFF0000u) + ubits(p1[k] & 0xFFFF0000u)
                            + ubits(p2[k] & 0xFFFF0000u) + ubits(p3[k] & 0xFFFF0000u);
        }
    }
    for (; e + 4 < end; e += 8) {
        const int s0 = e_src[e], s1 = e_src[e + 4];
        uint4 u0 = *reinterpret_cast<const uint4*>(X + (size_t)s0 * 128 + off);
        uint4 u1 = *reinterpret_cast<const uint4*>(X + (size_t)s1 * 128 + off);
        const unsigned int* p0 = (const unsigned int*)&u0;
        const unsigned int* p1 = (const unsigned int*)&u1;
#pragma unroll
        for (int k = 0; k < 4; ++k) {
            acc[2 * k]     += ubits(p0[k] << 16) + ubits(p1[k] << 16);
            acc[2 * k + 1] += ubits(p0[k] & 0xFFFF0000u) + ubits(p1[k] & 0xFFFF0000u);
        }
    }
    if (e < end) {
        const int s = e_src[e];
        uint4 u = *reinterpret_cast<const uint4*>(X + (size_t)s * 128 + off);
        const unsigned int* p = (const unsigned int*)&u;
#pragma unroll
        for (int k = 0; k < 4; ++k) {
            acc[2 * k]     += ubits(p[k] << 16);
            acc[2 * k + 1] += ubits(p[k] & 0xFFFF0000u);
        }
    }

#pragma unroll
    for (int k = 0; k < 8; ++k) acc[k] += __shfl_xor(acc[k], 32);
#pragma unroll
    for (int k = 0; k < 8; ++k) acc[k] += __shfl_xor(acc[k], 16);

    if (qw == 0) {
        ushort4 o0, o1;
        o0.x = f2b(acc[0]); o0.y = f2b(acc[1]); o0.z = f2b(acc[2]); o0.w = f2b(acc[3]);
        o1.x = f2b(acc[4]); o1.y = f2b(acc[5]); o1.z = f2b(acc[6]); o1.w = f2b(acc[7]);
        unsigned short* p = agg + (size_t)node * 128 + off;
        *reinterpret_cast<ushort4*>(p) = o0;
        *reinterpret_cast<ushort4*>(p + 4) = o1;
    }
}

// ---------------------------------------------------------------------------
// Fused MLP v3 (round 9, kept): weights in VGPRs, loaded once per block from
// fragment-order packs. Barriers: A-ready, T-ready (+1 FUSE).
// LDS: A[64][136]=17408 | T[64][264]=33792 (disjoint) | FUSE Hf[64][136].
// ---------------------------------------------------------------------------
template <bool FUSE>
__global__ __launch_bounds__(256, 2) void mlp_fused(
    const unsigned short* __restrict__ X, const unsigned short* __restrict__ Wp1,
    const float* __restrict__ b1, const unsigned short* __restrict__ Wp2,
    const float* __restrict__ b2, unsigned short* __restrict__ Y,
    const unsigned short* __restrict__ Wfct, const float* __restrict__ bfc,
    float* __restrict__ out, int M) {
    __shared__ __align__(16) char smem[FUSE ? 68608 : 51200];
    unsigned short* A  = (unsigned short*)smem;             // [64][136]
    unsigned short* T  = (unsigned short*)(smem + 17408);   // [64][264]
    unsigned short* Hf = (unsigned short*)(smem + 51200);   // [64][136] FUSE

    const int tid = threadIdx.x;
    const int m0 = blockIdx.x * 64;
    const int lane = tid & 63, w = tid >> 6;
    const int qm = lane & 15, quad = lane >> 4;

    // ---- stage-1 weight fragments -> VGPRs (16 coalesced 16B loads) ----
    short8 wb1[16];
#pragma unroll
    for (int v = 0; v < 16; ++v)
        wb1[v] = *reinterpret_cast<const short8*>(Wp1 + ((v * 256 + tid) << 3));

    // ---- load A (64 x 128 bf16) ----
#pragma unroll
    for (int j = 0; j < 4; ++j) {
        int i = j * 256 + tid;
        int r = i >> 4, c8 = (i & 15) << 3;
        uint4 v = {0, 0, 0, 0};
        if (m0 + r < M) v = *reinterpret_cast<const uint4*>(X + (size_t)(m0 + r) * 128 + c8);
        *reinterpret_cast<uint4*>(&A[r * 136 + c8]) = v;
    }
    __syncthreads();   // A ready

    // ---- stage 1: T = relu(A @ W1 + b1), sequential over c halves ----
#pragma unroll
    for (int c = 0; c < 2; ++c) {
        floatx4 acc1[4][2];
#pragma unroll
        for (int mt = 0; mt < 4; ++mt)
#pragma unroll
            for (int nt = 0; nt < 2; ++nt) acc1[mt][nt] = {0.f, 0.f, 0.f, 0.f};
#pragma unroll
        for (int ks = 0; ks < 4; ++ks) {
            const int kb = ks * 32 + quad * 8;
            short8 a[4];
#pragma unroll
            for (int mt = 0; mt < 4; ++mt)
                a[mt] = *reinterpret_cast<const short8*>(&A[(mt * 16 + qm) * 136 + kb]);
#pragma unroll
            for (int mt = 0; mt < 4; ++mt)
#pragma unroll
                for (int nt = 0; nt < 2; ++nt)
                    acc1[mt][nt] = __builtin_amdgcn_mfma_f32_16x16x32_bf16(
                        a[mt], wb1[c * 8 + ks * 2 + nt], acc1[mt][nt], 0, 0, 0);
        }
        // epilogue for this half: T cols c*128..+128 (A,T disjoint — no sync)
#pragma unroll
        for (int nt = 0; nt < 2; ++nt) {
            const int jcol = c * 128 + w * 32 + nt * 16 + qm;
            const float bj = b1[jcol];
#pragma unroll
            for (int mt = 0; mt < 4; ++mt)
#pragma unroll
                for (int r = 0; r < 4; ++r)
                    T[(mt * 16 + quad * 4 + r) * 264 + jcol] =
                        f2b(fmaxf(acc1[mt][nt][r] + bj, 0.f));
        }
    }

    // ---- stage-2 weight fragments -> VGPRs (32 coalesced 16B loads) ----
    short8 wb2[32];
#pragma unroll
    for (int v = 0; v < 32; ++v)
        wb2[v] = *reinterpret_cast<const short8*>(Wp2 + ((v * 256 + tid) << 3));
    __syncthreads();   // T ready

    // ---- stage 2: h = relu(T @ W2 + b2) ----
#pragma unroll
    for (int c2 = 0; c2 < 4; ++c2) {
        floatx4 acc2[2];
        acc2[0] = {0.f, 0.f, 0.f, 0.f};
        acc2[1] = {0.f, 0.f, 0.f, 0.f};
#pragma unroll
        for (int ks = 0; ks < 8; ++ks) {
            const int kb = ks * 32 + quad * 8;
            short8 t0 = *reinterpret_cast<const short8*>(&T[((w & 1) * 32 + qm) * 264 + kb]);
            short8 t1 = *reinterpret_cast<const short8*>(&T[((w & 1) * 32 + 16 + qm) * 264 + kb]);
            acc2[0] = __builtin_amdgcn_mfma_f32_16x16x32_bf16(t0, wb2[c2 * 8 + ks], acc2[0], 0, 0, 0);
            acc2[1] = __builtin_amdgcn_mfma_f32_16x16x32_bf16(t1, wb2[c2 * 8 + ks], acc2[1], 0, 0, 0);
        }

        const int ncol = c2 * 32 + (w >> 1) * 16 + qm;   // global h col
        const float bj = b2[ncol];
        if (!FUSE) {
#pragma unroll
            for (int mt2 = 0; mt2 < 2; ++mt2)
#pragma unroll
                for (int r = 0; r < 4; ++r) {
                    int row = m0 + (w & 1) * 32 + mt2 * 16 + quad * 4 + r;
                    if (row < M)
                        Y[(size_t)row * 128 + ncol] = f2b(fmaxf(acc2[mt2][r] + bj, 0.f));
                }
        } else {
#pragma unroll
            for (int mt2 = 0; mt2 < 2; ++mt2)
#pragma unroll
                for (int r = 0; r < 4; ++r)
                    Hf[((w & 1) * 32 + mt2 * 16 + quad * 4 + r) * 136 + ncol] =
                        f2b(fmaxf(acc2[mt2][r] + bj, 0.f));
        }
    }

    if (FUSE) {
        __syncthreads();   // Hf ready
        // ---- classifier: out = h @ Wfct^T + bfc, single pass over Hf ----
        floatx4 cacc[3];
#pragma unroll
        for (int nt = 0; nt < 3; ++nt) cacc[nt] = {0.f, 0.f, 0.f, 0.f};
#pragma unroll
        for (int c2 = 0; c2 < 4; ++c2) {
            short8 hf = *reinterpret_cast<const short8*>(
                &Hf[(w * 16 + qm) * 136 + c2 * 32 + quad * 8]);
#pragma unroll
            for (int nt = 0; nt < 3; ++nt) {
                short8 bf = *reinterpret_cast<const short8*>(
                    Wfct + (nt * 16 + qm) * 128 + c2 * 32 + quad * 8);
                cacc[nt] = __builtin_amdgcn_mfma_f32_16x16x32_bf16(hf, bf, cacc[nt], 0, 0, 0);
            }
        }
#pragma unroll
        for (int nt = 0; nt < 3; ++nt) {
            int col = nt * 16 + qm;
            if (col < 40) {
                const float bj = bfc[col];
#pragma unroll
                for (int r = 0; r < 4; ++r) {
                    int row = m0 + w * 16 + quad * 4 + r;
                    if (row < M) out[(size_t)row * 40 + col] = cacc[nt][r] + bj;
                }
            }
        }
    }
}

// ---------------------------------------------------------------------------
extern "C" void kernel_launch(void* const* d_in, const int* in_sizes, int n_in,
                              void* d_out, int out_size, void* d_ws, size_t ws_size,
                              hipStream_t stream) {
    const float* x   = (const float*)d_in[0];
    const int*   ei  = (const int*)d_in[1];
    const float* W11 = (const float*)d_in[2];
    const float* b11 = (const float*)d_in[3];
    const float* W12 = (const float*)d_in[4];
    const float* b12 = (const float*)d_in[5];
    const float* W21 = (const float*)d_in[6];
    const float* b21 = (const float*)d_in[7];
    const float* W22 = (const float*)d_in[8];
    const float* b22 = (const float*)d_in[9];
    const float* Wfc = (const float*)d_in[10];
    const float* bfc = (const float*)d_in[11];
    float* out = (float*)d_out;

    const int* srcv = ei;
    const int* dstv = ei + N_EDGES;

    unsigned short* agg  = (unsigned short*)d_ws;               // 50000*128 bf16
    unsigned short* h    = agg + (size_t)N_NODES * 128;
    unsigned short* xb   = h   + (size_t)N_NODES * 128;
    unsigned short* Wp11 = xb  + (size_t)N_NODES * 128;         // 32768
    unsigned short* Wp12 = Wp11 + 32768;                        // 65536 (2x dup)
    unsigned short* Wp21 = Wp12 + 65536;                        // 32768
    unsigned short* Wp22 = Wp21 + 32768;                        // 65536
    unsigned short* Wfct = Wp22 + 65536;                        // 48*128
    int* bcount  = (int*)(Wfct + 48 * 128);                     // 392 (pad 512)
    int* row_ptr = bcount + 512;                                // 392*129 (pad 50688)
    int* e_src   = row_ptr + 50688;                             // 392*2560
    int* bufc    = e_src + (size_t)NBUCK * CAPB;                // 392*2560

    // ---- zero reservation counters (tiny, capture-safe) ----
    hipMemsetAsync(bcount, 0, NBUCK * sizeof(int), stream);

    // ---- K1: single-pass scatter (hist + reserve + place) + x->bf16 ----
    scatter_all<<<NSB + 3125, 256, 0, stream>>>(srcv, dstv, x, bcount, bufc, xb);

    // ---- K2: per-bucket finish + weight packing cover ----
    finish_conv<<<NBUCK + 792, 256, 0, stream>>>(
        bcount, bufc, e_src, row_ptr,
        W11, W12, W21, W22, Wfc,
        Wp11, Wp12, Wp21, Wp22, Wfct);

    const int agg_blocks = N_NODES * 64 / 256;        // 12500, one wave per node
    const int mlp_blocks = (N_NODES + 63) / 64;       // 782

    // ---- layer 1 ----
    agg_bf16q<<<agg_blocks, 256, 0, stream>>>(xb, row_ptr, e_src, agg);
    mlp_fused<false><<<mlp_blocks, 256, 0, stream>>>(
        agg, Wp11, b11, Wp12, b12, h, nullptr, nullptr, nullptr, N_NODES);
    // ---- layer 2 + classifier ----
    agg_bf16q<<<agg_blocks, 256, 0, stream>>>(h, row_ptr, e_src, agg);
    mlp_fused<true><<<mlp_blocks, 256, 0, stream>>>(
        agg, Wp21, b21, Wp22, b22, nullptr, Wfct, bfc, out, N_NODES);
}

// Round 12
// 221.477 us; speedup vs baseline: 1.1026x; 1.0060x over previous
//
#include <hip/hip_runtime.h>

#define N_NODES 50000
#define N_EDGES 800000
#define NBUCK   392           // buckets of 128 nodes (dst >> 7)
#define EPB     2048          // edges per scatter block
#define NSB     391           // scatter blocks = ceil(800000/2048)
#define CAPB    2560          // per-bucket capacity (mean ~2041, +11 sigma)

typedef __attribute__((ext_vector_type(8))) short short8;
typedef __attribute__((ext_vector_type(4))) float floatx4;

__device__ __forceinline__ float ubits(unsigned int b) {
    union { unsigned int i; float f; } v;
    v.i = b;
    return v.f;
}
__device__ __forceinline__ unsigned short f2b(float f) {  // round-nearest-even
    union { float f; unsigned int i; } v;
    v.f = f;
    unsigned int r = v.i + 0x7FFFu + ((v.i >> 16) & 1u);
    return (unsigned short)(r >> 16);
}

// ---------------------------------------------------------------------------
// Fragment-order weight packs (round 9, kept). MLP holds weights in VGPRs;
// pack layout Wp[(v*256 + tid)*8 + j] makes the per-block register load
// fully coalesced (one 16B load per (v, tid)).
// ---------------------------------------------------------------------------
__device__ __forceinline__ void pack_s1(const float* __restrict__ W,
                                        unsigned short* __restrict__ Wp,
                                        int blk, int tid) {
    int p = blk * 256 + tid;                 // [0, 32768)
    int j = p & 7, t2 = (p >> 3) & 255, v = p >> 11;
    int w = t2 >> 6, lane = t2 & 63, quad = lane >> 4, qm = lane & 15;
    int c = v >> 3, ks = (v >> 1) & 3, nt = v & 1;
    int k = ks * 32 + quad * 8 + j;
    int n = c * 128 + w * 32 + nt * 16 + qm;
    Wp[p] = f2b(W[k * 256 + n]);
}
__device__ __forceinline__ void pack_s2(const float* __restrict__ W,
                                        unsigned short* __restrict__ Wp,
                                        int blk, int tid) {
    int p = blk * 256 + tid;                 // [0, 65536)
    int j = p & 7, t2 = (p >> 3) & 255, v2 = p >> 11;
    int w = t2 >> 6, lane = t2 & 63, quad = lane >> 4, qm = lane & 15;
    int c2 = v2 >> 3, ks = v2 & 7;
    int k = ks * 32 + quad * 8 + j;
    int n = c2 * 32 + (w >> 1) * 16 + qm;
    Wp[p] = f2b(W[k * 128 + n]);
}

// ---------------------------------------------------------------------------
// K1: single-pass scatter (vectorized edge loads) + x->bf16 cover.
// Thread t_e owns 8 contiguous edges -> 2+2 uint4 loads.
// bcount must be zeroed before launch (hipMemsetAsync).
// ---------------------------------------------------------------------------
__global__ __launch_bounds__(256) void scatter_all(
    const int* __restrict__ srcv, const int* __restrict__ dstv,
    const float* __restrict__ x,
    int* __restrict__ bcount, int* __restrict__ bufc,
    unsigned short* __restrict__ xb) {
    const int bid = blockIdx.x;
    const int tid = threadIdx.x;
    if (bid < NSB) {
        __shared__ int hist[NBUCK];
        __shared__ int base[NBUCK];
        const int te = bid * 256 + tid;          // valid < 100000
        const bool ok = te < (N_EDGES / 8);
        int d[8], s[8];
        if (ok) {
            const uint4* dp = reinterpret_cast<const uint4*>(dstv + (size_t)te * 8);
            const uint4* sp = reinterpret_cast<const uint4*>(srcv + (size_t)te * 8);
            uint4 d0 = dp[0], d1 = dp[1], s0 = sp[0], s1 = sp[1];
            d[0] = d0.x; d[1] = d0.y; d[2] = d0.z; d[3] = d0.w;
            d[4] = d1.x; d[5] = d1.y; d[6] = d1.z; d[7] = d1.w;
            s[0] = s0.x; s[1] = s0.y; s[2] = s0.z; s[3] = s0.w;
            s[4] = s1.x; s[5] = s1.y; s[6] = s1.z; s[7] = s1.w;
        }
        for (int i = tid; i < NBUCK; i += 256) hist[i] = 0;
        __syncthreads();
        if (ok) {
#pragma unroll
            for (int j = 0; j < 8; ++j) atomicAdd(&hist[d[j] >> 7], 1);
        }
        __syncthreads();
        for (int i = tid; i < NBUCK; i += 256) {
            int c = hist[i];
            base[i] = c ? atomicAdd(&bcount[i], c) : 0;
            hist[i] = 0;
        }
        __syncthreads();
        if (ok) {
#pragma unroll
            for (int j = 0; j < 8; ++j) {
                int b = d[j] >> 7;
                int r = atomicAdd(&hist[b], 1);
                bufc[b * CAPB + base[b] + r] = s[j] | ((d[j] & 127) << 16);
            }
        }
    } else {
        int i = (bid - NSB) * 256 + tid;             // 800000 groups of 8
        const float4 a = *reinterpret_cast<const float4*>(x + (size_t)i * 8);
        const float4 b = *reinterpret_cast<const float4*>(x + (size_t)i * 8 + 4);
        ushort4 u0, u1;
        u0.x = f2b(a.x); u0.y = f2b(a.y); u0.z = f2b(a.z); u0.w = f2b(a.w);
        u1.x = f2b(b.x); u1.y = f2b(b.y); u1.z = f2b(b.z); u1.w = f2b(b.w);
        *reinterpret_cast<ushort4*>(xb + (size_t)i * 8) = u0;
        *reinterpret_cast<ushort4*>(xb + (size_t)i * 8 + 4) = u1;
    }
}

// ---------------------------------------------------------------------------
// K2: per-bucket finish (uint4 bufc reads; e_src stored as USHORT — round 12:
// halves agg-side e_src traffic; src < 65536 always) + weight packing cover.
// ---------------------------------------------------------------------------
__global__ __launch_bounds__(256) void finish_conv(
    const int* __restrict__ bcount, const int* __restrict__ bufc,
    unsigned short* __restrict__ e_src, int* __restrict__ row_ptr,
    const float* __restrict__ W11, const float* __restrict__ W12,
    const float* __restrict__ W21, const float* __restrict__ W22,
    const float* __restrict__ Wfc,
    unsigned short* __restrict__ Wp11, unsigned short* __restrict__ Wp12,
    unsigned short* __restrict__ Wp21, unsigned short* __restrict__ Wp22,
    unsigned short* __restrict__ Wfct) {
    const int bid = blockIdx.x;
    const int tid = threadIdx.x;
    if (bid < NBUCK) {
        __shared__ int nc[128];
        __shared__ int ps[128];
        const int b = bid;
        const int S = bcount[b];
        const int gb = b * CAPB;
        const uint4* b4 = reinterpret_cast<const uint4*>(bufc + gb);
        const int nv = S >> 2;
        if (tid < 128) nc[tid] = 0;
        __syncthreads();
        for (int i = tid; i < nv; i += 256) {
            uint4 v = b4[i];
            atomicAdd(&nc[(v.x >> 16) & 127], 1);
            atomicAdd(&nc[(v.y >> 16) & 127], 1);
            atomicAdd(&nc[(v.z >> 16) & 127], 1);
            atomicAdd(&nc[(v.w >> 16) & 127], 1);
        }
        for (int t = (nv << 2) + tid; t < S; t += 256)
            atomicAdd(&nc[(bufc[gb + t] >> 16) & 127], 1);
        __syncthreads();
        if (tid < 128) ps[tid] = nc[tid];
        __syncthreads();
        for (int off = 1; off < 128; off <<= 1) {
            int u = (tid >= off && tid < 128) ? ps[tid - off] : 0;
            __syncthreads();
            if (tid < 128) ps[tid] += u;
            __syncthreads();
        }
        if (tid < 128) {
            const int excl = ps[tid] - nc[tid];
            row_ptr[b * 129 + tid] = gb + excl;
            nc[tid] = gb + excl;                 // absolute cursor
        }
        if (tid == 0) row_ptr[b * 129 + 128] = gb + S;
        __syncthreads();
        for (int i = tid; i < nv; i += 256) {
            uint4 v = b4[i];
            int p;
            p = atomicAdd(&nc[(v.x >> 16) & 127], 1); e_src[p] = (unsigned short)(v.x & 0xFFFF);
            p = atomicAdd(&nc[(v.y >> 16) & 127], 1); e_src[p] = (unsigned short)(v.y & 0xFFFF);
            p = atomicAdd(&nc[(v.z >> 16) & 127], 1); e_src[p] = (unsigned short)(v.z & 0xFFFF);
            p = atomicAdd(&nc[(v.w >> 16) & 127], 1); e_src[p] = (unsigned short)(v.w & 0xFFFF);
        }
        for (int t = (nv << 2) + tid; t < S; t += 256) {
            int pv = bufc[gb + t];
            int pos = atomicAdd(&nc[(pv >> 16) & 127], 1);
            e_src[pos] = (unsigned short)(pv & 0xFFFF);
        }
    } else if (bid < NBUCK + 128) {
        pack_s1(W11, Wp11, bid - NBUCK, tid);
    } else if (bid < NBUCK + 384) {
        pack_s2(W12, Wp12, bid - NBUCK - 128, tid);
    } else if (bid < NBUCK + 512) {
        pack_s1(W21, Wp21, bid - NBUCK - 384, tid);
    } else if (bid < NBUCK + 768) {
        pack_s2(W22, Wp22, bid - NBUCK - 512, tid);
    } else {
        int idx = (bid - NBUCK - 768) * 256 + tid;   // 6144 = 48*128
        int n = idx >> 7, k = idx & 127;
        Wfct[idx] = (n < 40) ? f2b(Wfc[k * 40 + n]) : (unsigned short)0;
    }
}

// ---------------------------------------------------------------------------
// aggregate: agg[i] = x[i] + sum_{e in row i} x[e_src[e]]  — one wave/node.
// Quarter-wave split (16 lanes x ushort8 = 256B row), 4 edge streams/wave,
// row_ptr 129-strided per bucket. e_src is ushort (round 12).
// ---------------------------------------------------------------------------
__global__ __launch_bounds__(256) void agg_bf16q(const unsigned short* __restrict__ X,
                                                 const int* __restrict__ row_ptr,
                                                 const unsigned short* __restrict__ e_src,
                                                 unsigned short* __restrict__ agg) {
    const int node = (blockIdx.x * 256 + threadIdx.x) >> 6;
    const int lane = threadIdx.x & 63;
    const int qw = lane >> 4, ql = lane & 15;
    const size_t off = (size_t)ql * 8;

    const int rp = node + (node >> 7);
    const int beg = row_ptr[rp], end = row_ptr[rp + 1];
    float acc[8];
#pragma unroll
    for (int k = 0; k < 8; ++k) acc[k] = 0.f;

    if (qw == 0) {
        uint4 u = *reinterpret_cast<const uint4*>(X + (size_t)node * 128 + off);
        const unsigned int* up = (const unsigned int*)&u;
#pragma unroll
        for (int k = 0; k < 4; ++k) {
            acc[2 * k]     += ubits(up[k] << 16);
            acc[2 * k + 1] += ubits(up[k] & 0xFFFF0000u);
        }
    }

    int e = beg + qw;
    for (; e + 12 < end; e += 16) {
        const int s0 = e_src[e], s1 = e_src[e + 4], s2 = e_src[e + 8], s3 = e_src[e + 12];
        uint4 u0 = *reinterpret_cast<const uint4*>(X + (size_t)s0 * 128 + off);
        uint4 u1 = *reinterpret_cast<const uint4*>(X + (size_t)s1 * 128 + off);
        uint4 u2 = *reinterpret_cast<const uint4*>(X + (size_t)s2 * 128 + off);
        uint4 u3 = *reinterpret_cast<const uint4*>(X + (size_t)s3 * 128 + off);
        const unsigned int* p0 = (const unsigned int*)&u0;
        const unsigned int* p1 = (const unsigned int*)&u1;
        const unsigned int* p2 = (const unsigned int*)&u2;
        const unsigned int* p3 = (const unsigned int*)&u3;
#pragma unroll
        for (int k = 0; k < 4; ++k) {
            acc[2 * k]     += ubits(p0[k] << 16) + ubits(p1[k] << 16)
                            + ubits(p2[k] << 16) + ubits(p3[k] << 16);
            acc[2 * k + 1] += ubits(p0[k] & 0xFFFF0000u) + ubits(p1[k] & 0xFFFF0000u)
                            + ubits(p2[k] & 0xFFFF0000u) + ubits(p3[k] & 0xFFFF0000u);
        }
    }
    for (; e + 4 < end; e += 8) {
        const int s0 = e_src[e], s1 = e_src[e + 4];
        uint4 u0 = *reinterpret_cast<const uint4*>(X + (size_t)s0 * 128 + off);
        uint4 u1 = *reinterpret_cast<const uint4*>(X + (size_t)s1 * 128 + off);
        const unsigned int* p0 = (const unsigned int*)&u0;
        const unsigned int* p1 = (const unsigned int*)&u1;
#pragma unroll
        for (int k = 0; k < 4; ++k) {
            acc[2 * k]     += ubits(p0[k] << 16) + ubits(p1[k] << 16);
            acc[2 * k + 1] += ubits(p0[k] & 0xFFFF0000u) + ubits(p1[k] & 0xFFFF0000u);
        }
    }
    if (e < end) {
        const int s = e_src[e];
        uint4 u = *reinterpret_cast<const uint4*>(X + (size_t)s * 128 + off);
        const unsigned int* p = (const unsigned int*)&u;
#pragma unroll
        for (int k = 0; k < 4; ++k) {
            acc[2 * k]     += ubits(p[k] << 16);
            acc[2 * k + 1] += ubits(p[k] & 0xFFFF0000u);
        }
    }

#pragma unroll
    for (int k = 0; k < 8; ++k) acc[k] += __shfl_xor(acc[k], 32);
#pragma unroll
    for (int k = 0; k < 8; ++k) acc[k] += __shfl_xor(acc[k], 16);

    if (qw == 0) {
        ushort4 o0, o1;
        o0.x = f2b(acc[0]); o0.y = f2b(acc[1]); o0.z = f2b(acc[2]); o0.w = f2b(acc[3]);
        o1.x = f2b(acc[4]); o1.y = f2b(acc[5]); o1.z = f2b(acc[6]); o1.w = f2b(acc[7]);
        unsigned short* p = agg + (size_t)node * 128 + off;
        *reinterpret_cast<ushort4*>(p) = o0;
        *reinterpret_cast<ushort4*>(p + 4) = o1;
    }
}

// ---------------------------------------------------------------------------
// Fused MLP v3.1 (round 12): weights in VGPRs (round 9).  FUSE change: Hf
// OVERLAPS A (A's last read is stage-1 MFMA, before the T-ready barrier;
// Hf's first write is after it) -> FUSE LDS 68608 -> 51200 -> 3 blocks/CU
// (was 2), cutting mlp2's occupancy rounds 1.53 -> 1.02.
// LDS: A[64][136]=17408 (=Hf in FUSE) | T[64][264]=33792.
// ---------------------------------------------------------------------------
template <bool FUSE>
__global__ __launch_bounds__(256, 2) void mlp_fused(
    const unsigned short* __restrict__ X, const unsigned short* __restrict__ Wp1,
    const float* __restrict__ b1, const unsigned short* __restrict__ Wp2,
    const float* __restrict__ b2, unsigned short* __restrict__ Y,
    const unsigned short* __restrict__ Wfct, const float* __restrict__ bfc,
    float* __restrict__ out, int M) {
    __shared__ __align__(16) char smem[51200];
    unsigned short* A  = (unsigned short*)smem;             // [64][136] stage 1
    unsigned short* T  = (unsigned short*)(smem + 17408);   // [64][264]
    unsigned short* Hf = (unsigned short*)smem;             // [64][136] FUSE (over A)

    const int tid = threadIdx.x;
    const int m0 = blockIdx.x * 64;
    const int lane = tid & 63, w = tid >> 6;
    const int qm = lane & 15, quad = lane >> 4;

    // ---- stage-1 weight fragments -> VGPRs (16 coalesced 16B loads) ----
    short8 wb1[16];
#pragma unroll
    for (int v = 0; v < 16; ++v)
        wb1[v] = *reinterpret_cast<const short8*>(Wp1 + ((v * 256 + tid) << 3));

    // ---- load A (64 x 128 bf16) ----
#pragma unroll
    for (int j = 0; j < 4; ++j) {
        int i = j * 256 + tid;
        int r = i >> 4, c8 = (i & 15) << 3;
        uint4 v = {0, 0, 0, 0};
        if (m0 + r < M) v = *reinterpret_cast<const uint4*>(X + (size_t)(m0 + r) * 128 + c8);
        *reinterpret_cast<uint4*>(&A[r * 136 + c8]) = v;
    }
    __syncthreads();   // A ready

    // ---- stage 1: T = relu(A @ W1 + b1), sequential over c halves ----
#pragma unroll
    for (int c = 0; c < 2; ++c) {
        floatx4 acc1[4][2];
#pragma unroll
        for (int mt = 0; mt < 4; ++mt)
#pragma unroll
            for (int nt = 0; nt < 2; ++nt) acc1[mt][nt] = {0.f, 0.f, 0.f, 0.f};
#pragma unroll
        for (int ks = 0; ks < 4; ++ks) {
            const int kb = ks * 32 + quad * 8;
            short8 a[4];
#pragma unroll
            for (int mt = 0; mt < 4; ++mt)
                a[mt] = *reinterpret_cast<const short8*>(&A[(mt * 16 + qm) * 136 + kb]);
#pragma unroll
            for (int mt = 0; mt < 4; ++mt)
#pragma unroll
                for (int nt = 0; nt < 2; ++nt)
                    acc1[mt][nt] = __builtin_amdgcn_mfma_f32_16x16x32_bf16(
                        a[mt], wb1[c * 8 + ks * 2 + nt], acc1[mt][nt], 0, 0, 0);
        }
        // epilogue for this half: T cols c*128..+128 (A,T disjoint — no sync)
#pragma unroll
        for (int nt = 0; nt < 2; ++nt) {
            const int jcol = c * 128 + w * 32 + nt * 16 + qm;
            const float bj = b1[jcol];
#pragma unroll
            for (int mt = 0; mt < 4; ++mt)
#pragma unroll
                for (int r = 0; r < 4; ++r)
                    T[(mt * 16 + quad * 4 + r) * 264 + jcol] =
                        f2b(fmaxf(acc1[mt][nt][r] + bj, 0.f));
        }
    }

    // ---- stage-2 weight fragments -> VGPRs (32 coalesced 16B loads) ----
    short8 wb2[32];
#pragma unroll
    for (int v = 0; v < 32; ++v)
        wb2[v] = *reinterpret_cast<const short8*>(Wp2 + ((v * 256 + tid) << 3));
    __syncthreads();   // T ready; A dead from here (Hf may overwrite)

    // ---- stage 2: h = relu(T @ W2 + b2) ----
#pragma unroll
    for (int c2 = 0; c2 < 4; ++c2) {
        floatx4 acc2[2];
        acc2[0] = {0.f, 0.f, 0.f, 0.f};
        acc2[1] = {0.f, 0.f, 0.f, 0.f};
#pragma unroll
        for (int ks = 0; ks < 8; ++ks) {
            const int kb = ks * 32 + quad * 8;
            short8 t0 = *reinterpret_cast<const short8*>(&T[((w & 1) * 32 + qm) * 264 + kb]);
            short8 t1 = *reinterpret_cast<const short8*>(&T[((w & 1) * 32 + 16 + qm) * 264 + kb]);
            acc2[0] = __builtin_amdgcn_mfma_f32_16x16x32_bf16(t0, wb2[c2 * 8 + ks], acc2[0], 0, 0, 0);
            acc2[1] = __builtin_amdgcn_mfma_f32_16x16x32_bf16(t1, wb2[c2 * 8 + ks], acc2[1], 0, 0, 0);
        }

        const int ncol = c2 * 32 + (w >> 1) * 16 + qm;   // global h col
        const float bj = b2[ncol];
        if (!FUSE) {
#pragma unroll
            for (int mt2 = 0; mt2 < 2; ++mt2)
#pragma unroll
                for (int r = 0; r < 4; ++r) {
                    int row = m0 + (w & 1) * 32 + mt2 * 16 + quad * 4 + r;
                    if (row < M)
                        Y[(size_t)row * 128 + ncol] = f2b(fmaxf(acc2[mt2][r] + bj, 0.f));
                }
        } else {
#pragma unroll
            for (int mt2 = 0; mt2 < 2; ++mt2)
#pragma unroll
                for (int r = 0; r < 4; ++r)
                    Hf[((w & 1) * 32 + mt2 * 16 + quad * 4 + r) * 136 + ncol] =
                        f2b(fmaxf(acc2[mt2][r] + bj, 0.f));
        }
    }

    if (FUSE) {
        __syncthreads();   // Hf ready
        // ---- classifier: out = h @ Wfct^T + bfc, single pass over Hf ----
        floatx4 cacc[3];
#pragma unroll
        for (int nt = 0; nt < 3; ++nt) cacc[nt] = {0.f, 0.f, 0.f, 0.f};
#pragma unroll
        for (int c2 = 0; c2 < 4; ++c2) {
            short8 hf = *reinterpret_cast<const short8*>(
                &Hf[(w * 16 + qm) * 136 + c2 * 32 + quad * 8]);
#pragma unroll
            for (int nt = 0; nt < 3; ++nt) {
                short8 bf = *reinterpret_cast<const short8*>(
                    Wfct + (nt * 16 + qm) * 128 + c2 * 32 + quad * 8);
                cacc[nt] = __builtin_amdgcn_mfma_f32_16x16x32_bf16(hf, bf, cacc[nt], 0, 0, 0);
            }
        }
#pragma unroll
        for (int nt = 0; nt < 3; ++nt) {
            int col = nt * 16 + qm;
            if (col < 40) {
                const float bj = bfc[col];
#pragma unroll
                for (int r = 0; r < 4; ++r) {
                    int row = m0 + w * 16 + quad * 4 + r;
                    if (row < M) out[(size_t)row * 40 + col] = cacc[nt][r] + bj;
                }
            }
        }
    }
}

// ---------------------------------------------------------------------------
extern "C" void kernel_launch(void* const* d_in, const int* in_sizes, int n_in,
                              void* d_out, int out_size, void* d_ws, size_t ws_size,
                              hipStream_t stream) {
    const float* x   = (const float*)d_in[0];
    const int*   ei  = (const int*)d_in[1];
    const float* W11 = (const float*)d_in[2];
    const float* b11 = (const float*)d_in[3];
    const float* W12 = (const float*)d_in[4];
    const float* b12 = (const float*)d_in[5];
    const float* W21 = (const float*)d_in[6];
    const float* b21 = (const float*)d_in[7];
    const float* W22 = (const float*)d_in[8];
    const float* b22 = (const float*)d_in[9];
    const float* Wfc = (const float*)d_in[10];
    const float* bfc = (const float*)d_in[11];
    float* out = (float*)d_out;

    const int* srcv = ei;
    const int* dstv = ei + N_EDGES;

    unsigned short* agg  = (unsigned short*)d_ws;               // 50000*128 bf16
    unsigned short* h    = agg + (size_t)N_NODES * 128;
    unsigned short* xb   = h   + (size_t)N_NODES * 128;
    unsigned short* Wp11 = xb  + (size_t)N_NODES * 128;         // 32768
    unsigned short* Wp12 = Wp11 + 32768;                        // 65536 (2x dup)
    unsigned short* Wp21 = Wp12 + 65536;                        // 32768
    unsigned short* Wp22 = Wp21 + 32768;                        // 65536
    unsigned short* Wfct = Wp22 + 65536;                        // 48*128
    int* bcount  = (int*)(Wfct + 48 * 128);                     // 392 (pad 512)
    int* row_ptr = bcount + 512;                                // 392*129 (pad 50688)
    unsigned short* e_src = (unsigned short*)(row_ptr + 50688); // 392*2560 ushort
    int* bufc    = (int*)(e_src + (size_t)NBUCK * CAPB);        // 392*2560 int (16B-aligned)

    // ---- zero reservation counters (tiny, capture-safe) ----
    hipMemsetAsync(bcount, 0, NBUCK * sizeof(int), stream);

    // ---- K1: single-pass scatter (hist + reserve + place) + x->bf16 ----
    scatter_all<<<NSB + 3125, 256, 0, stream>>>(srcv, dstv, x, bcount, bufc, xb);

    // ---- K2: per-bucket finish + weight packing cover ----
    finish_conv<<<NBUCK + 792, 256, 0, stream>>>(
        bcount, bufc, e_src, row_ptr,
        W11, W12, W21, W22, Wfc,
        Wp11, Wp12, Wp21, Wp22, Wfct);

    const int agg_blocks = N_NODES * 64 / 256;        // 12500, one wave per node
    const int mlp_blocks = (N_NODES + 63) / 64;       // 782

    // ---- layer 1 ----
    agg_bf16q<<<agg_blocks, 256, 0, stream>>>(xb, row_ptr, e_src, agg);
    mlp_fused<false><<<mlp_blocks, 256, 0, stream>>>(
        agg, Wp11, b11, Wp12, b12, h, nullptr, nullptr, nullptr, N_NODES);
    // ---- layer 2 + classifier ----
    agg_bf16q<<<agg_blocks, 256, 0, stream>>>(h, row_ptr, e_src, agg);
    mlp_fused<true><<<mlp_blocks, 256, 0, stream>>>(
        agg, Wp21, b21, Wp22, b22, nullptr, Wfct, bfc, out, N_NODES);
}